// Round 15
// baseline (219.049 us; speedup 1.0000x reference)
//
#include <hip/hip_runtime.h>
#include <hip/hip_bf16.h>
#include <math.h>

// ---------------- problem constants ----------------
#define B_   16
#define NQ_  300
#define D_   256
#define NH_  8
#define DH_  32
#define L_   3
#define P_   4
#define FFN_ 1024
#define S_   8400   // 80*80 + 40*40 + 20*20
#define ROWS_ (B_*NQ_)        // 4800
#define NB_   (ROWS_*D_)      // 1228800 floats per (B,NQ,D) buffer

typedef __attribute__((ext_vector_type(4))) unsigned short ushort4_t;
typedef __attribute__((ext_vector_type(8))) unsigned short ushort8_t;
typedef __attribute__((ext_vector_type(8))) short bf16x8;
typedef __attribute__((ext_vector_type(4))) float f32x4;

__device__ inline unsigned short f2b(float f) {
    __hip_bfloat16 h = __float2bfloat16(f);
    return __builtin_bit_cast(unsigned short, h);
}
__device__ inline float b2f(unsigned short u) {
    union { unsigned u; float f; } c; c.u = ((unsigned)u) << 16; return c.f;
}

// ---------------- fused weight prep: 10 transposes + 2 bias concats ----------
__global__ __launch_bounds__(256) void prep_kernel(
    const float* __restrict__ wq, const float* __restrict__ wk,
    const float* __restrict__ wv, const float* __restrict__ wo,
    const float* __restrict__ w_val, const float* __restrict__ w_out,
    const float* __restrict__ w_off, const float* __restrict__ w_aw,
    const float* __restrict__ w_fc1, const float* __restrict__ w_fc2,
    const float* __restrict__ bq, const float* __restrict__ bk,
    const float* __restrict__ b_off, const float* __restrict__ b_aw,
    unsigned short* __restrict__ wtqk, unsigned short* __restrict__ wtv,
    unsigned short* __restrict__ wto, unsigned short* __restrict__ wtval,
    unsigned short* __restrict__ wtout, unsigned short* __restrict__ wtoa,
    unsigned short* __restrict__ wtfc1, unsigned short* __restrict__ wtfc2,
    float* __restrict__ bqk, float* __restrict__ boa)
{
    const int bid = blockIdx.x;
    if (bid >= 968) {
        int idx = (bid - 968)*256 + threadIdx.x;   // 0..1023
        if (idx < 512) bqk[idx] = (idx < 256) ? bq[idx] : bk[idx-256];
        else { int j = idx - 512; if (j < 288) boa[j] = (j < 192) ? b_off[j] : b_aw[j-192]; }
        return;
    }
    const float* src; unsigned short* dst; int K, N, t;
    if      (bid < 64)  { src=wq;    dst=wtqk;         K=256;  N=256;  t=bid; }
    else if (bid < 128) { src=wk;    dst=wtqk+65536;   K=256;  N=256;  t=bid-64; }
    else if (bid < 192) { src=wv;    dst=wtv;          K=256;  N=256;  t=bid-128; }
    else if (bid < 256) { src=wo;    dst=wto;          K=256;  N=256;  t=bid-192; }
    else if (bid < 320) { src=w_val; dst=wtval;        K=256;  N=256;  t=bid-256; }
    else if (bid < 384) { src=w_out; dst=wtout;        K=256;  N=256;  t=bid-320; }
    else if (bid < 432) { src=w_off; dst=wtoa;         K=256;  N=192;  t=bid-384; }
    else if (bid < 456) { src=w_aw;  dst=wtoa+49152;   K=256;  N=96;   t=bid-432; }
    else if (bid < 712) { src=w_fc1; dst=wtfc1;        K=256;  N=1024; t=bid-456; }
    else                { src=w_fc2; dst=wtfc2;        K=1024; N=256;  t=bid-712; }

    __shared__ unsigned short tl[32][33];
    int tid = threadIdx.x;
    int tx = tid & 31, ty = tid >> 5;           // ty 0..7
    int ntx = N >> 5;
    int n0 = (t % ntx) * 32, k0 = (t / ntx) * 32;
    #pragma unroll
    for (int i = 0; i < 4; ++i)
        tl[tx][ty + i*8] = f2b(src[(size_t)(k0 + ty + i*8)*N + n0 + tx]);
    __syncthreads();
    #pragma unroll
    for (int i = 0; i < 4; ++i)
        dst[(size_t)(n0 + ty + i*8)*K + k0 + tx] = tl[ty + i*8][tx];
}

// ================= 64x128 GEMM macros (4 waves 2x2 of 32x64) ==================
#define GEMM_PREAMBLE()                                                        \
    const int tid  = threadIdx.x;                                              \
    const int lane = tid & 63;                                                 \
    const int w    = tid >> 6;                                                 \
    const int wr   = w >> 1, wc = w & 1;                                       \
    const int m0   = blockIdx.y * 64;                                          \
    const int n0   = blockIdx.x * 128;                                         \
    const int fr   = lane & 15, fq = lane >> 4;                                \
    const int arow = tid >> 2, aseg = (tid & 3) * 8;                           \
    const int brow = tid >> 1, bseg = (tid & 1) * 16;                          \
    const bool a_ok = (m0 + arow) < M;                                         \
    const bool b_ok = (n0 + brow) < N;                                         \
    const float*          aptr  = A  + (size_t)(m0 + arow)*K + aseg;           \
    const float*          aptr2 = A2 ? A2 + (size_t)(m0 + arow)*K + aseg : (const float*)0; \
    const unsigned short* bptr  = WT + (size_t)(n0 + brow)*K + bseg;           \
    f32x4 acc[2][4];                                                           \
    _Pragma("unroll") for (int m = 0; m < 2; ++m)                              \
        _Pragma("unroll") for (int n = 0; n < 4; ++n)                          \
            acc[m][n] = (f32x4){0.f, 0.f, 0.f, 0.f};                           \
    float4 avA0, avB0, avA1, avB1;                                             \
    ushort8_t bvA0, bvB0, bvA1, bvB1;

#define GEMM_LOAD(avA, avB, bvA, bvB, kk) do {                                 \
    if (a_ok) {                                                                \
        avA = *(const float4*)(aptr + (kk));                                   \
        avB = *(const float4*)(aptr + (kk) + 4);                               \
        if (aptr2) {                                                           \
            float4 x2 = *(const float4*)(aptr2 + (kk));                        \
            float4 y2 = *(const float4*)(aptr2 + (kk) + 4);                    \
            avA.x += x2.x; avA.y += x2.y; avA.z += x2.z; avA.w += x2.w;        \
            avB.x += y2.x; avB.y += y2.y; avB.z += y2.z; avB.w += y2.w;        \
        }                                                                      \
    } else { avA = (float4){0,0,0,0}; avB = (float4){0,0,0,0}; }               \
    if (b_ok) { bvA = *(const ushort8_t*)(bptr + (kk));                        \
                bvB = *(const ushort8_t*)(bptr + (kk) + 8); }                  \
    else { _Pragma("unroll") for (int j = 0; j < 8; ++j){bvA[j]=0;bvB[j]=0;} } \
} while (0)

#define GEMM_STORE_LDS(avA, avB, bvA, bvB) do {                                \
    ushort8_t ac;                                                              \
    ac[0]=f2b(avA.x); ac[1]=f2b(avA.y); ac[2]=f2b(avA.z); ac[3]=f2b(avA.w);    \
    ac[4]=f2b(avB.x); ac[5]=f2b(avB.y); ac[6]=f2b(avB.z); ac[7]=f2b(avB.w);    \
    *(ushort8_t*)&As[arow][aseg]     = ac;                                     \
    *(ushort8_t*)&Bs[brow][bseg]     = bvA;                                    \
    *(ushort8_t*)&Bs[brow][bseg + 8] = bvB;                                    \
} while (0)

#define GEMM_COMPUTE() do {                                                    \
    bf16x8 af[2], bfv[4];                                                      \
    _Pragma("unroll") for (int m = 0; m < 2; ++m)                              \
        af[m] = *(const bf16x8*)&As[wr*32 + m*16 + fr][fq*8];                  \
    _Pragma("unroll") for (int n = 0; n < 4; ++n)                              \
        bfv[n] = *(const bf16x8*)&Bs[wc*64 + n*16 + fr][fq*8];                 \
    _Pragma("unroll") for (int m = 0; m < 2; ++m)                              \
        _Pragma("unroll") for (int n = 0; n < 4; ++n)                          \
            acc[m][n] = __builtin_amdgcn_mfma_f32_16x16x32_bf16(               \
                af[m], bfv[n], acc[m][n], 0, 0, 0);                            \
} while (0)

#define GEMM_KLOOP()                                                           \
    GEMM_LOAD(avA0, avB0, bvA0, bvB0, 0);                                      \
    for (int k0 = 0; k0 < K; k0 += 64) {                                       \
        __syncthreads();                                                       \
        GEMM_STORE_LDS(avA0, avB0, bvA0, bvB0);                                \
        GEMM_LOAD(avA1, avB1, bvA1, bvB1, k0 + 32);                            \
        __syncthreads();                                                       \
        GEMM_COMPUTE();                                                        \
        __syncthreads();                                                       \
        GEMM_STORE_LDS(avA1, avB1, bvA1, bvB1);                                \
        if (k0 + 64 < K) GEMM_LOAD(avA0, avB0, bvA0, bvB0, k0 + 64);           \
        __syncthreads();                                                       \
        GEMM_COMPUTE();                                                        \
    }

// ---------------- generic GEMM: C = (A [+A2]) @ WT^T + bias, opt relu --------
__global__ __launch_bounds__(256) void gemm_mfma64(
    const float* __restrict__ A, const float* __restrict__ A2,
    const unsigned short* __restrict__ WT,
    const float* __restrict__ bias, float* __restrict__ C,
    int M, int N, int K, int relu)
{
    __shared__ unsigned short As[64][40];
    __shared__ unsigned short Bs[128][40];
    GEMM_PREAMBLE();
    GEMM_KLOOP();

    #pragma unroll
    for (int n = 0; n < 4; ++n) {
        int col = n0 + wc*64 + n*16 + fr;
        if (col < N) {
            float bcol = bias[col];
            #pragma unroll
            for (int m = 0; m < 2; ++m) {
                int rbase = m0 + wr*32 + m*16 + fq*4;
                #pragma unroll
                for (int r = 0; r < 4; ++r) {
                    int row = rbase + r;
                    if (row < M) {
                        float vv = acc[m][n][r] + bcol;
                        if (relu) vv = fmaxf(vv, 0.f);
                        C[(size_t)row * N + col] = vv;
                    }
                }
            }
        }
    }
}

// ---------------- stage1: val (whole-N 64x256, 51KB LDS) + QK + V ------------
// blocks 0..2099: value GEMM -> bf16 head-major (LDS-coalesced epilogue);
// 2100..2399: QK; 2400..2549: V.
__global__ __launch_bounds__(256) void stage1_kernel(
    const float* __restrict__ ehs, const float* __restrict__ h_in,
    const float* __restrict__ pos,
    const unsigned short* __restrict__ wtval, const float* __restrict__ b_val,
    unsigned short* __restrict__ val_bf,
    const unsigned short* __restrict__ wtqk, const float* __restrict__ bqk,
    float* __restrict__ buf_qk,
    const unsigned short* __restrict__ wtv, const float* __restrict__ bv,
    float* __restrict__ buf_v)
{
    __shared__ unsigned short LDS[25600];   // 51.2 KB -> 3 blocks/CU

    const int bid  = blockIdx.x;
    const int tid  = threadIdx.x;
    const int lane = tid & 63;
    const int w    = tid >> 6;
    const int wr   = w >> 1, wc = w & 1;
    const int fr   = lane & 15, fq = lane >> 4;

    if (bid < 2100) {
        // ------- value path: 64 rows x 256 cols, K chunks of 64 -------
        unsigned short (&As2)[2][64][40]  = *(unsigned short(*)[2][64][40])(LDS);
        unsigned short (&Bs2)[2][256][40] = *(unsigned short(*)[2][256][40])(LDS + 5120);
        const int m0 = bid * 64;

        f32x4 acc[2][8];
        #pragma unroll
        for (int m = 0; m < 2; ++m)
            #pragma unroll
            for (int n = 0; n < 8; ++n)
                acc[m][n] = (f32x4){0.f, 0.f, 0.f, 0.f};

        for (int kc = 0; kc < 4; ++kc) {
            const int kbase = kc * 64;
            __syncthreads();
            // stage A chunk: 64x64 fp32 -> bf16 (2 units/thread)
            #pragma unroll
            for (int i = 0; i < 2; ++i) {
                int uf = i*256 + tid;              // 0..511
                int row = uf >> 3, j = uf & 7;
                const float* src = ehs + (size_t)(m0 + row)*256 + kbase + j*8;
                float4 x = *(const float4*)src;
                float4 y = *(const float4*)(src + 4);
                ushort8_t u;
                u[0]=f2b(x.x); u[1]=f2b(x.y); u[2]=f2b(x.z); u[3]=f2b(x.w);
                u[4]=f2b(y.x); u[5]=f2b(y.y); u[6]=f2b(y.z); u[7]=f2b(y.w);
                *(ushort8_t*)&As2[j>>2][row][(j&3)*8] = u;
            }
            // stage B chunk: 256x64 bf16 (8 units/thread)
            #pragma unroll
            for (int i = 0; i < 8; ++i) {
                int uf = i*256 + tid;              // 0..2047
                int row = uf >> 3, j = uf & 7;
                ushort8_t u = *(const ushort8_t*)(wtval + (size_t)row*256 + kbase + j*8);
                *(ushort8_t*)&Bs2[j>>2][row][(j&3)*8] = u;
            }
            __syncthreads();
            // compute: 2 k-steps x 16 MFMA
            #pragma unroll
            for (int ks = 0; ks < 2; ++ks) {
                bf16x8 af[2], bfv[8];
                #pragma unroll
                for (int m = 0; m < 2; ++m)
                    af[m] = *(const bf16x8*)&As2[ks][wr*32 + m*16 + fr][fq*8];
                #pragma unroll
                for (int n = 0; n < 8; ++n)
                    bfv[n] = *(const bf16x8*)&Bs2[ks][wc*128 + n*16 + fr][fq*8];
                #pragma unroll
                for (int m = 0; m < 2; ++m)
                    #pragma unroll
                    for (int n = 0; n < 8; ++n)
                        acc[m][n] = __builtin_amdgcn_mfma_f32_16x16x32_bf16(
                            af[m], bfv[n], acc[m][n], 0, 0, 0);
            }
        }

        // ------- epilogue: acc -> LDS tile -> coalesced 64B head-chunk writes -
        unsigned short (&Ot)[64][264] = *(unsigned short(*)[64][264])(LDS);
        __syncthreads();   // compute-phase LDS reads complete
        #pragma unroll
        for (int n = 0; n < 8; ++n) {
            int col = wc*128 + n*16 + fr;          // 0..255
            float bcol = b_val[col];
            #pragma unroll
            for (int m = 0; m < 2; ++m) {
                int rb = wr*32 + m*16 + fq*4;
                #pragma unroll
                for (int r = 0; r < 4; ++r)
                    Ot[rb + r][col] = f2b(acc[m][n][r] + bcol);
            }
        }
        __syncthreads();
        #pragma unroll
        for (int i = 0; i < 2; ++i) {
            int idx = i*256 + tid;                 // 0..511
            int hh = idx >> 6;                     // 0..7
            int rr = idx & 63;                     // consecutive tid -> consecutive ss
            unsigned row = m0 + rr;
            unsigned bb = row / (unsigned)S_;
            unsigned ss = row - bb * (unsigned)S_;
            unsigned short* dst = val_bf + ((size_t)(bb*NH_ + hh)*S_ + ss)*DH_;
            const unsigned short* src = &Ot[rr][hh*32];
            #pragma unroll
            for (int j = 0; j < 4; ++j)
                *(ushort8_t*)(dst + j*8) = *(const ushort8_t*)(src + j*8);
        }
    } else {
        // ------- qkv path: 64x128 tile, proven 2-barrier K-loop -------
        unsigned short (&As)[64][40]  = *(unsigned short(*)[64][40])(LDS);
        unsigned short (&Bs)[128][40] = *(unsigned short(*)[128][40])(LDS + 2560);

        const int t = bid - 2100;
        int m0, n0, Ncols;
        const float* A2p = nullptr;
        const unsigned short* Bp; const float* bias; float* C;
        if (t < 300) {
            m0 = (t >> 2)*64; n0 = (t & 3)*128;
            A2p = pos; Bp = wtqk; bias = bqk; C = buf_qk; Ncols = 512;
        } else {
            int tt = t - 300;
            m0 = (tt >> 1)*64; n0 = (tt & 1)*128;
            Bp = wtv; bias = bv; C = buf_v; Ncols = 256;
        }

        const int arow = tid >> 2, aseg = (tid & 3) * 8;
        const int brow = tid >> 1, bseg = (tid & 1) * 16;
        const bool a_ok = true, b_ok = true;
        const int K = 256;
        const float*          aptr  = h_in + (size_t)(m0 + arow)*256 + aseg;
        const float*          aptr2 = A2p ? A2p + (size_t)(m0 + arow)*256 + aseg : (const float*)0;
        const unsigned short* bptr  = Bp + (size_t)(n0 + brow)*256 + bseg;

        f32x4 acc[2][4];
        #pragma unroll
        for (int m = 0; m < 2; ++m)
            #pragma unroll
            for (int n = 0; n < 4; ++n)
                acc[m][n] = (f32x4){0.f, 0.f, 0.f, 0.f};
        float4 avA0, avB0, avA1, avB1;
        ushort8_t bvA0, bvB0, bvA1, bvB1;

        GEMM_KLOOP();

        #pragma unroll
        for (int n = 0; n < 4; ++n) {
            int col = n0 + wc*64 + n*16 + fr;
            float bcol = bias[col];
            #pragma unroll
            for (int m = 0; m < 2; ++m) {
                int rbase = m0 + wr*32 + m*16 + fq*4;
                #pragma unroll
                for (int r = 0; r < 4; ++r)
                    C[(size_t)(rbase + r) * Ncols + col] = acc[m][n][r] + bcol;
            }
        }
    }
}

// ---------------- fc1: GEMM + bias + relu -> bf16 out (exact shapes) ---------
__global__ __launch_bounds__(256) void gemm_relu_bf16(
    const float* __restrict__ A, const unsigned short* __restrict__ WT,
    const float* __restrict__ bias, unsigned short* __restrict__ OUT,
    int M, int N, int K)
{
    __shared__ unsigned short As[64][40];
    __shared__ unsigned short Bs[128][40];
    const float* A2 = nullptr;
    GEMM_PREAMBLE();
    GEMM_KLOOP();

    #pragma unroll
    for (int n = 0; n < 4; ++n) {
        int col = n0 + wc*64 + n*16 + fr;
        float bcol = bias[col];
        #pragma unroll
        for (int m = 0; m < 2; ++m) {
            int rbase = m0 + wr*32 + m*16 + fq*4;
            #pragma unroll
            for (int r = 0; r < 4; ++r)
                OUT[(size_t)(rbase + r) * N + col] = f2b(fmaxf(acc[m][n][r] + bcol, 0.f));
        }
    }
}

// ================= fused GEMM(N=256) + residual add + LayerNorm ==============
#define GLN16_COMPUTE() do {                                                   \
    bf16x8 af = *(const bf16x8*)&As[fr][fq*8];                                 \
    _Pragma("unroll") for (int n = 0; n < 4; ++n) {                            \
        bf16x8 bfv = *(const bf16x8*)&Bs[w*64 + n*16 + fr][fq*8];              \
        acc[n] = __builtin_amdgcn_mfma_f32_16x16x32_bf16(af, bfv, acc[n], 0, 0, 0); \
    }                                                                          \
} while (0)

#define GLN16_EPILOGUE()                                                       \
    float gcol[4], bcol2[4], biascol[4];                                       \
    _Pragma("unroll") for (int n = 0; n < 4; ++n) {                            \
        int col = w*64 + n*16 + fr;                                            \
        biascol[n] = bias[col]; gcol[n] = g[col]; bcol2[n] = bb[col];          \
    }                                                                          \
    _Pragma("unroll") for (int r = 0; r < 4; ++r) {                            \
        int row = fq*4 + r;                                                    \
        float s = 0.f, sq = 0.f;                                               \
        _Pragma("unroll") for (int n = 0; n < 4; ++n) {                        \
            int col = w*64 + n*16 + fr;                                        \
            float vv = acc[n][r] + biascol[n]                                  \
                     + X[(size_t)(m0 + row)*256 + col];                        \
            acc[n][r] = vv; s += vv; sq += vv*vv;                              \
        }                                                                      \
        s  += __shfl_xor(s, 1);  sq += __shfl_xor(sq, 1);                      \
        s  += __shfl_xor(s, 2);  sq += __shfl_xor(sq, 2);                      \
        s  += __shfl_xor(s, 4);  sq += __shfl_xor(sq, 4);                      \
        s  += __shfl_xor(s, 8);  sq += __shfl_xor(sq, 8);                      \
        if (fr == 0) { psum[row][w] = s; psq[row][w] = sq; }                   \
    }                                                                          \
    __syncthreads();                                                           \
    _Pragma("unroll") for (int r = 0; r < 4; ++r) {                            \
        int row = fq*4 + r;                                                    \
        float mean = (psum[row][0]+psum[row][1]+psum[row][2]+psum[row][3]) * (1.0f/256.0f); \
        float ex2  = (psq[row][0]+psq[row][1]+psq[row][2]+psq[row][3]) * (1.0f/256.0f);     \
        float rstd = rsqrtf(ex2 - mean*mean + 1e-5f);                          \
        _Pragma("unroll") for (int n = 0; n < 4; ++n) {                        \
            int col = w*64 + n*16 + fr;                                        \
            OUT[(size_t)(m0 + row)*256 + col] =                                \
                (acc[n][r] - mean)*rstd*gcol[n] + bcol2[n];                    \
        }                                                                      \
    }

__global__ __launch_bounds__(256) void gemm_ln_f32A(
    const float* __restrict__ A, const unsigned short* __restrict__ WT,
    const float* __restrict__ bias, const float* __restrict__ X,
    const float* __restrict__ g, const float* __restrict__ bb,
    float* __restrict__ OUT, int K)
{
    __shared__ unsigned short As[16][40];
    __shared__ unsigned short Bs[256][40];
    __shared__ float psum[16][4], psq[16][4];

    const int tid  = threadIdx.x;
    const int lane = tid & 63;
    const int w    = tid >> 6;
    const int m0   = blockIdx.x * 16;
    const int fr   = lane & 15, fq = lane >> 4;
    const bool astage = tid < 64;
    const int arow = (tid >> 2) & 15, aseg = (tid & 3) * 8;
    const float*          aptr = A  + (size_t)(m0 + arow)*K + aseg;
    const unsigned short* bptr = WT + (size_t)tid*K;

    f32x4 acc[4];
    #pragma unroll
    for (int n = 0; n < 4; ++n) acc[n] = (f32x4){0.f, 0.f, 0.f, 0.f};

    float4 a0x = {0,0,0,0}, a0y = {0,0,0,0}, a1x = {0,0,0,0}, a1y = {0,0,0,0};
    ushort8_t b0[4], b1[4];

    if (astage) { a0x = *(const float4*)(aptr); a0y = *(const float4*)(aptr + 4); }
    #pragma unroll
    for (int j = 0; j < 4; ++j) b0[j] = *(const ushort8_t*)(bptr + j*8);
    for (int k0 = 0; k0 < K; k0 += 64) {
        __syncthreads();
        if (astage) {
            ushort8_t ac;
            ac[0]=f2b(a0x.x); ac[1]=f2b(a0x.y); ac[2]=f2b(a0x.z); ac[3]=f2b(a0x.w);
            ac[4]=f2b(a0y.x); ac[5]=f2b(a0y.y); ac[6]=f2b(a0y.z); ac[7]=f2b(a0y.w);
            *(ushort8_t*)&As[arow][aseg] = ac;
        }
        #pragma unroll
        for (int j = 0; j < 4; ++j) *(ushort8_t*)&Bs[tid][j*8] = b0[j];
        if (astage) { a1x = *(const float4*)(aptr + k0 + 32); a1y = *(const float4*)(aptr + k0 + 36); }
        #pragma unroll
        for (int j = 0; j < 4; ++j) b1[j] = *(const ushort8_t*)(bptr + k0 + 32 + j*8);
        __syncthreads();
        GLN16_COMPUTE();
        __syncthreads();
        if (astage) {
            ushort8_t ac;
            ac[0]=f2b(a1x.x); ac[1]=f2b(a1x.y); ac[2]=f2b(a1x.z); ac[3]=f2b(a1x.w);
            ac[4]=f2b(a1y.x); ac[5]=f2b(a1y.y); ac[6]=f2b(a1y.z); ac[7]=f2b(a1y.w);
            *(ushort8_t*)&As[arow][aseg] = ac;
        }
        #pragma unroll
        for (int j = 0; j < 4; ++j) *(ushort8_t*)&Bs[tid][j*8] = b1[j];
        if (k0 + 64 < K) {
            if (astage) { a0x = *(const float4*)(aptr + k0 + 64); a0y = *(const float4*)(aptr + k0 + 68); }
            #pragma unroll
            for (int j = 0; j < 4; ++j) b0[j] = *(const ushort8_t*)(bptr + k0 + 64 + j*8);
        }
        __syncthreads();
        GLN16_COMPUTE();
    }

    GLN16_EPILOGUE();
}

__global__ __launch_bounds__(256) void gemm_ln_bf16A(
    const unsigned short* __restrict__ A, const unsigned short* __restrict__ WT,
    const float* __restrict__ bias, const float* __restrict__ X,
    const float* __restrict__ g, const float* __restrict__ bb,
    float* __restrict__ OUT, int K)
{
    __shared__ unsigned short As[16][40];
    __shared__ unsigned short Bs[256][40];
    __shared__ float psum[16][4], psq[16][4];

    const int tid  = threadIdx.x;
    const int lane = tid & 63;
    const int w    = tid >> 6;
    const int m0   = blockIdx.x * 16;
    const int fr   = lane & 15, fq = lane >> 4;
    const bool astage = tid < 64;
    const int arow = (tid >> 2) & 15, aseg = (tid & 3) * 8;
    const unsigned short* aptr = A  + (size_t)(m0 + arow)*K + aseg;
    const unsigned short* bptr = WT + (size_t)tid*K;

    f32x4 acc[4];
    #pragma unroll
    for (int n = 0; n < 4; ++n) acc[n] = (f32x4){0.f, 0.f, 0.f, 0.f};

    ushort8_t a0, a1, b0[4], b1[4];
    #pragma unroll
    for (int j = 0; j < 8; ++j) { a0[j] = 0; a1[j] = 0; }

    if (astage) a0 = *(const ushort8_t*)(aptr);
    #pragma unroll
    for (int j = 0; j < 4; ++j) b0[j] = *(const ushort8_t*)(bptr + j*8);
    for (int k0 = 0; k0 < K; k0 += 64) {
        __syncthreads();
        if (astage) *(ushort8_t*)&As[arow][aseg] = a0;
        #pragma unroll
        for (int j = 0; j < 4; ++j) *(ushort8_t*)&Bs[tid][j*8] = b0[j];
        if (astage) a1 = *(const ushort8_t*)(aptr + k0 + 32);
        #pragma unroll
        for (int j = 0; j < 4; ++j) b1[j] = *(const ushort8_t*)(bptr + k0 + 32 + j*8);
        __syncthreads();
        GLN16_COMPUTE();
        __syncthreads();
        if (astage) *(ushort8_t*)&As[arow][aseg] = a1;
        #pragma unroll
        for (int j = 0; j < 4; ++j) *(ushort8_t*)&Bs[tid][j*8] = b1[j];
        if (k0 + 64 < K) {
            if (astage) a0 = *(const ushort8_t*)(aptr + k0 + 64);
            #pragma unroll
            for (int j = 0; j < 4; ++j) b0[j] = *(const ushort8_t*)(bptr + k0 + 64 + j*8);
        }
        __syncthreads();
        GLN16_COMPUTE();
    }

    GLN16_EPILOGUE();
}

// ---------------- self attention via MFMA ----------------
__global__ __launch_bounds__(256) void self_attn_kernel(
    const float* __restrict__ qk, const float* __restrict__ v,
    float* __restrict__ sa)
{
    __shared__ unsigned short k_sw[304*32];      // K bf16, 16B-unit XOR swizzled
    __shared__ unsigned short vt[32][312];       // V^T bf16: [d][key]
    __shared__ unsigned short p_all[4][16][312]; // per-wave P: [q_local][key]

    const int bid  = blockIdx.x;
    const int part = bid % 5;
    const int bh   = bid / 5;
    const int h    = bh & 7;
    const int b    = bh >> 3;
    const int tid  = threadIdx.x;
    const int lane = tid & 63;
    const int w    = tid >> 6;
    const int g    = lane >> 4;   // 0..3
    const int fr   = lane & 15;

    const size_t qbase = (size_t)b*NQ_*512 + h*DH_;
    const size_t kbase = qbase + 256;
    const size_t vbase = (size_t)b*NQ_*D_ + h*DH_;
    const size_t sbase = (size_t)b*NQ_*D_ + h*DH_;

    for (int i = tid; i < 1216; i += 256) {
        int r = i >> 2, u = i & 3;
        ushort8_t kb;
        if (r < NQ_) {
            const float* p8 = qk + kbase + (size_t)r*512 + u*8;
            float4 a0 = *(const float4*)p8;
            float4 a1 = *(const float4*)(p8 + 4);
            kb[0]=f2b(a0.x); kb[1]=f2b(a0.y); kb[2]=f2b(a0.z); kb[3]=f2b(a0.w);
            kb[4]=f2b(a1.x); kb[5]=f2b(a1.y); kb[6]=f2b(a1.z); kb[7]=f2b(a1.w);
        } else {
            #pragma unroll
            for (int j = 0; j < 8; ++j) kb[j] = 0;
        }
        int su = u ^ ((r >> 1) & 3);
        *(ushort8_t*)&k_sw[r*32 + su*8] = kb;
    }
    for (int i = tid; i < 1216; i += 256) {
        int kk = i >> 2, u = i & 3;
        if (kk < NQ_) {
            const float* p8 = v + vbase + (size_t)kk*D_ + u*8;
            float4 a0 = *(const float4*)p8;
            float4 a1 = *(const float4*)(p8 + 4);
            float f[8] = {a0.x,a0.y,a0.z,a0.w,a1.x,a1.y,a1.z,a1.w};
            #pragma unroll
            for (int j = 0; j < 8; ++j) vt[u*8 + j][kk] = f2b(f[j]);
        } else {
            #pragma unroll
            for (int j = 0; j < 8; ++j) vt[u*8 + j][kk] = 0;
        }
    }
    __syncthreads();

    const int q0 = part*64 + w*16;
    const int qi = q0 + fr;
    bf16x8 qf;
    if (qi < NQ_) {
        const float scale = 0.17677669529663687f;
        const float* p8 = qk + qbase + (size_t)qi*512 + g*8;
        float4 a0 = *(const float4*)p8;
        float4 a1 = *(const float4*)(p8 + 4);
        qf[0]=(short)f2b(a0.x*scale); qf[1]=(short)f2b(a0.y*scale);
        qf[2]=(short)f2b(a0.z*scale); qf[3]=(short)f2b(a0.w*scale);
        qf[4]=(short)f2b(a1.x*scale); qf[5]=(short)f2b(a1.y*scale);
        qf[6]=(short)f2b(a1.z*scale); qf[7]=(short)f2b(a1.w*scale);
    } else {
        #pragma unroll
        for (int j = 0; j < 8; ++j) qf[j] = 0;
    }

    const int ksw_u = g ^ ((fr >> 1) & 3);
    f32x4 acc[19];
    #pragma unroll
    for (int t = 0; t < 19; ++t) acc[t] = (f32x4){0.f,0.f,0.f,0.f};
    #pragma unroll
    for (int t = 0; t < 19; ++t) {
        int row = t*16 + fr;
        bf16x8 kf = *(const bf16x8*)&k_sw[row*32 + ksw_u*8];
        acc[t] = __builtin_amdgcn_mfma_f32_16x16x32_bf16(kf, qf, acc[t], 0, 0, 0);
    }
    if (g == 3) acc[18] = (f32x4){-1e30f, -1e30f, -1e30f, -1e30f};

    float m = -1e30f;
    #pragma unroll
    for (int t = 0; t < 19; ++t) {
        #pragma unroll
        for (int r = 0; r < 4; ++r) m = fmaxf(m, acc[t][r]);
    }
    m = fmaxf(m, __shfl_xor(m, 16));
    m = fmaxf(m, __shfl_xor(m, 32));
    float lsum = 0.f;
    #pragma unroll
    for (int t = 0; t < 19; ++t) {
        #pragma unroll
        for (int r = 0; r < 4; ++r) {
            float e = __expf(acc[t][r] - m);
            acc[t][r] = e;
            lsum += e;
        }
    }
    lsum += __shfl_xor(lsum, 16);
    lsum += __shfl_xor(lsum, 32);
    float inv = 1.0f / lsum;

    #pragma unroll
    for (int t = 0; t < 19; ++t) {
        ushort4_t pw = { f2b(acc[t][0]*inv), f2b(acc[t][1]*inv),
                         f2b(acc[t][2]*inv), f2b(acc[t][3]*inv) };
        *(ushort4_t*)&p_all[w][fr][t*16 + g*4] = pw;
    }

    f32x4 o0 = (f32x4){0.f,0.f,0.f,0.f};
    f32x4 o1 = (f32x4){0.f,0.f,0.f,0.f};
    #pragma unroll
    for (int ks = 0; ks < 10; ++ks) {
        int kb = ks*32 + g*8;
        bf16x8 pf, vf0, vf1;
        if (kb < 304) {
            pf  = *(const bf16x8*)&p_all[w][fr][kb];
            vf0 = *(const bf16x8*)&vt[fr][kb];
            vf1 = *(const bf16x8*)&vt[16 + fr][kb];
        } else {
            #pragma unroll
            for (int j = 0; j < 8; ++j) { pf[j] = 0; vf0[j] = 0; vf1[j] = 0; }
        }
        o0 = __builtin_amdgcn_mfma_f32_16x16x32_bf16(pf, vf0, o0, 0, 0, 0);
        o1 = __builtin_amdgcn_mfma_f32_16x16x32_bf16(pf, vf1, o1, 0, 0, 0);
    }

    #pragma unroll
    for (int r = 0; r < 4; ++r) {
        int qo = q0 + g*4 + r;
        if (qo < NQ_) {
            sa[sbase + (size_t)qo*D_ + fr]      = o0[r];
            sa[sbase + (size_t)qo*D_ + 16 + fr] = o1[r];
        }
    }
}

// ---------------- deformable bilinear sampling: 2 d's per thread -------------
__global__ __launch_bounds__(256) void deform_kernel(
    const unsigned short* __restrict__ value, const float* __restrict__ oa,
    const float* __restrict__ refp, float* __restrict__ dout)
{
    int gid = blockIdx.x*256 + threadIdx.x;
    int l16 = gid & 15;
    int grp = gid >> 4;            // (b*NQ+q)*8 + h
    int h = grp & 7;
    int bq = grp >> 3;
    int qq = bq % NQ_;
    int b  = bq / NQ_;
    int d0 = l16*2;

    const int starts[3] = {0, 6400, 8000};
    const int Hs[3] = {80, 40, 20};

    const float* offp = oa + (size_t)(b*NQ_+qq)*288 + h*24;
    const float* awp  = oa + (size_t)(b*NQ_+qq)*288 + 192 + h*12;
    const float* refq = refp + (size_t)(b*NQ_+qq)*(L_*2);
    const unsigned short* vb = value + ((size_t)(b*NH_ + h)*S_)*DH_ + d0;

    float av[12];
    float mx = -1e30f;
    #pragma unroll
    for (int i = 0; i < 12; ++i) { av[i] = awp[i]; mx = fmaxf(mx, av[i]); }
    float ssum = 0.f;
    #pragma unroll
    for (int i = 0; i < 12; ++i) { av[i] = __expf(av[i]-mx); ssum += av[i]; }
    float sinv = 1.f / ssum;

    float acc0 = 0.f, acc1 = 0.f;
    #pragma unroll
    for (int l = 0; l < L_; l++) {
        int Hl = Hs[l], Wl = Hs[l];
        float rx = refq[l*2+0], ry = refq[l*2+1];
        const unsigned short* vlb = vb + (size_t)starts[l]*DH_;
        #pragma unroll
        for (int p = 0; p < P_; p++) {
            float ox = offp[(l*P_+p)*2+0], oy = offp[(l*P_+p)*2+1];
            float a  = av[l*P_+p] * sinv;
            float x = (rx + ox/(float)Wl)*(float)Wl - 0.5f;
            float y = (ry + oy/(float)Hl)*(float)Hl - 0.5f;
            float x0 = floorf(x), y0 = floorf(y);
            #pragma unroll
            for (int dy = 0; dy < 2; dy++) {
                #pragma unroll
                for (int dx = 0; dx < 2; dx++) {
                    float xi = x0 + dx, yi = y0 + dy;
                    float wgt = (1.f - fabsf(x-xi))*(1.f - fabsf(y-yi));
                    bool valid = (xi >= 0.f) && (xi < (float)Wl) && (yi >= 0.f) && (yi < (float)Hl);
                    if (valid && wgt != 0.f) {
                        int ix = (int)xi, iy = (int)yi;
                        unsigned u = *(const unsigned*)(vlb + (size_t)(iy*Wl + ix)*DH_);
                        float aw2 = a * wgt;
                        acc0 += aw2 * b2f((unsigned short)(u & 0xffff));
                        acc1 += aw2 * b2f((unsigned short)(u >> 16));
                    }
                }
            }
        }
    }
    float2 o = { acc0, acc1 };
    *(float2*)&dout[(size_t)grp*32 + d0] = o;
}

// ---------------- launch ----------------
extern "C" void kernel_launch(void* const* d_in, const int* in_sizes, int n_in,
                              void* d_out, int out_size, void* d_ws, size_t ws_size,
                              hipStream_t stream) {
    (void)in_sizes; (void)n_in; (void)out_size; (void)ws_size;
    const float* h_in  = (const float*)d_in[0];
    const float* pos   = (const float*)d_in[1];
    const float* ehs   = (const float*)d_in[2];
    const float* refp  = (const float*)d_in[3];
    // d_in[4] = spatial_shapes (hardcoded)
    const float* wq    = (const float*)d_in[5];
    const float* bq    = (const float*)d_in[6];
    const float* wk    = (const float*)d_in[7];
    const float* bk    = (const float*)d_in[8];
    const float* wv    = (const float*)d_in[9];
    const float* bv    = (const float*)d_in[10];
    const float* wo    = (const float*)d_in[11];
    const float* bo    = (const float*)d_in[12];
    const float* ln1g  = (const float*)d_in[13];
    const float* ln1b  = (const float*)d_in[14];
    const float* w_off = (const float*)d_in[15];
    const float* b_off = (const float*)d_in[16];
    const float* w_aw  = (const float*)d_in[17];
    const float* b_aw  = (const float*)d_in[18];
    const float* w_val = (const float*)d_in[19];
    const float* b_val = (const float*)d_in[20];
    const float* w_out = (const float*)d_in[21];
    const float* b_out = (const float*)d_in[22];
    const float* ln2g  = (const float*)d_in[23];
    const float* ln2b  = (const float*)d_in[24];
    const float* w_fc1 = (const float*)d_in[25];
    const float* b_fc1 = (const float*)d_in[26];
    const float* w_fc2 = (const float*)d_in[27];
    const float* b_fc2 = (const float*)d_in[28];
    const float* ln3g  = (const float*)d_in[29];
    const float* ln3b  = (const float*)d_in[30];
    float* out = (float*)d_out;

    float* ws = (float*)d_ws;
    float* buf_qk   = ws + 1*(size_t)NB_;          // fused q|k, 4800x512 (2 NB)
    float* buf_v    = ws + 3*(size_t)NB_;          // v proj; later deform out
    float* buf_sa   = ws + 4*(size_t)NB_;          // sa
    float* buf_h1   = ws + 6*(size_t)NB_;
    float* buf_h2   = ws + 7*(size_t)NB_;
    float* buf_oa   = ws + 8*(size_t)NB_;          // fused off|aw (raw), 4800x288
    unsigned short* fc1_bf = (unsigned short*)(ws + 9*(size_t)NB_ + NB_/2);   // 4800x1024 bf16
    unsigned short* val_bf = (unsigned short*)(ws + 13*(size_t)NB_ + NB_/2);  // (14 NB)

    unsigned short* wtb = (unsigned short*)(ws + 27*(size_t)NB_ + NB_/2);
    unsigned short* wtqk  = wtb;                   // 512x256
    unsigned short* wtv   = wtqk  + 131072;        // 256x256
    unsigned short* wto   = wtv   + 65536;
    unsigned short* wtval = wto   + 65536;
    unsigned short* wtout = wtval + 65536;
    unsigned short* wtoa  = wtout + 65536;         // 288x256
    unsigned short* wtfc1 = wtoa  + 73728;         // 1024x256
    unsigned short* wtfc2 = wtfc1 + 262144;        // 256x1024
    float* bqk = (float*)(wtfc2 + 262144);         // 512
    float* boa = bqk + 512;                        // 288

    dim3 blk(256);

    // ---- fused weight prep (1 launch) ----
    prep_kernel<<<dim3(972), blk, 0, stream>>>(
        wq, wk, wv, wo, w_val, w_out, w_off, w_aw, w_fc1, w_fc2,
        bq, bk, b_off, b_aw,
        wtqk, wtv, wto, wtval, wtout, wtoa, wtfc1, wtfc2, bqk, boa);

    // ---- stage1: value (whole-N, coalesced epilogue) + QK + V (2550 blocks) ----
    stage1_kernel<<<dim3(2550), blk, 0, stream>>>(
        ehs, h_in, pos, wtval, b_val, val_bf, wtqk, bqk, buf_qk, wtv, bv, buf_v);

    // self attention (MFMA)
    self_attn_kernel<<<dim3(B_*NH_*5), blk, 0, stream>>>(buf_qk, buf_v, buf_sa);
    // wo projection + residual + LN1 -> h1  (fused, 300 blocks)
    gemm_ln_f32A<<<dim3(ROWS_/16), blk, 0, stream>>>(
        buf_sa, wto, bo, h_in, ln1g, ln1b, buf_h1, 256);
    // fused offsets + attention weights (A2 = pos); aw stays RAW (softmax in deform)
    gemm_mfma64<<<dim3(3, 75), blk, 0, stream>>>(buf_h1, pos, wtoa, boa, buf_oa, ROWS_, 288, D_, 0);
    // deformable sampling (inline softmax, 2 d's/thread)
    deform_kernel<<<dim3(ROWS_*NH_*16/256), blk, 0, stream>>>(val_bf, buf_oa, refp, buf_v);
    // ca projection + residual + LN2 -> h2  (fused, 300 blocks)
    gemm_ln_f32A<<<dim3(ROWS_/16), blk, 0, stream>>>(
        buf_v, wtout, b_out, buf_h1, ln2g, ln2b, buf_h2, 256);
    // FFN: fc1 -> bf16, then fc2 + residual + LN3 -> out (fused, 300 blocks)
    gemm_relu_bf16<<<dim3(8, 75), blk, 0, stream>>>(buf_h2, wtfc1, b_fc1, fc1_bf, ROWS_, FFN_, D_);
    gemm_ln_bf16A<<<dim3(ROWS_/16), blk, 0, stream>>>(
        fc1_bf, wtfc2, b_fc2, buf_h2, ln3g, ln3b, out, FFN_);
}

// Round 16
// 210.444 us; speedup vs baseline: 1.0409x; 1.0409x over previous
//
#include <hip/hip_runtime.h>
#include <hip/hip_bf16.h>
#include <math.h>

// ---------------- problem constants ----------------
#define B_   16
#define NQ_  300
#define D_   256
#define NH_  8
#define DH_  32
#define L_   3
#define P_   4
#define FFN_ 1024
#define S_   8400   // 80*80 + 40*40 + 20*20
#define ROWS_ (B_*NQ_)        // 4800
#define NB_   (ROWS_*D_)      // 1228800 floats per (B,NQ,D) buffer

typedef __attribute__((ext_vector_type(4))) unsigned short ushort4_t;
typedef __attribute__((ext_vector_type(8))) unsigned short ushort8_t;
typedef __attribute__((ext_vector_type(8))) short bf16x8;
typedef __attribute__((ext_vector_type(4))) float f32x4;

__device__ inline unsigned short f2b(float f) {
    __hip_bfloat16 h = __float2bfloat16(f);
    return __builtin_bit_cast(unsigned short, h);
}
__device__ inline float b2f(unsigned short u) {
    union { unsigned u; float f; } c; c.u = ((unsigned)u) << 16; return c.f;
}

// ---------------- fused weight prep: 10 transposes + 2 bias concats ----------
__global__ __launch_bounds__(256) void prep_kernel(
    const float* __restrict__ wq, const float* __restrict__ wk,
    const float* __restrict__ wv, const float* __restrict__ wo,
    const float* __restrict__ w_val, const float* __restrict__ w_out,
    const float* __restrict__ w_off, const float* __restrict__ w_aw,
    const float* __restrict__ w_fc1, const float* __restrict__ w_fc2,
    const float* __restrict__ bq, const float* __restrict__ bk,
    const float* __restrict__ b_off, const float* __restrict__ b_aw,
    unsigned short* __restrict__ wtqk, unsigned short* __restrict__ wtv,
    unsigned short* __restrict__ wto, unsigned short* __restrict__ wtval,
    unsigned short* __restrict__ wtout, unsigned short* __restrict__ wtoa,
    unsigned short* __restrict__ wtfc1, unsigned short* __restrict__ wtfc2,
    float* __restrict__ bqk, float* __restrict__ boa)
{
    const int bid = blockIdx.x;
    if (bid >= 968) {
        int idx = (bid - 968)*256 + threadIdx.x;   // 0..1023
        if (idx < 512) bqk[idx] = (idx < 256) ? bq[idx] : bk[idx-256];
        else { int j = idx - 512; if (j < 288) boa[j] = (j < 192) ? b_off[j] : b_aw[j-192]; }
        return;
    }
    const float* src; unsigned short* dst; int K, N, t;
    if      (bid < 64)  { src=wq;    dst=wtqk;         K=256;  N=256;  t=bid; }
    else if (bid < 128) { src=wk;    dst=wtqk+65536;   K=256;  N=256;  t=bid-64; }
    else if (bid < 192) { src=wv;    dst=wtv;          K=256;  N=256;  t=bid-128; }
    else if (bid < 256) { src=wo;    dst=wto;          K=256;  N=256;  t=bid-192; }
    else if (bid < 320) { src=w_val; dst=wtval;        K=256;  N=256;  t=bid-256; }
    else if (bid < 384) { src=w_out; dst=wtout;        K=256;  N=256;  t=bid-320; }
    else if (bid < 432) { src=w_off; dst=wtoa;         K=256;  N=192;  t=bid-384; }
    else if (bid < 456) { src=w_aw;  dst=wtoa+49152;   K=256;  N=96;   t=bid-432; }
    else if (bid < 712) { src=w_fc1; dst=wtfc1;        K=256;  N=1024; t=bid-456; }
    else                { src=w_fc2; dst=wtfc2;        K=1024; N=256;  t=bid-712; }

    __shared__ unsigned short tl[32][33];
    int tid = threadIdx.x;
    int tx = tid & 31, ty = tid >> 5;           // ty 0..7
    int ntx = N >> 5;
    int n0 = (t % ntx) * 32, k0 = (t / ntx) * 32;
    #pragma unroll
    for (int i = 0; i < 4; ++i)
        tl[tx][ty + i*8] = f2b(src[(size_t)(k0 + ty + i*8)*N + n0 + tx]);
    __syncthreads();
    #pragma unroll
    for (int i = 0; i < 4; ++i)
        dst[(size_t)(n0 + ty + i*8)*K + k0 + tx] = tl[ty + i*8][tx];
}

// ================= 64x128 GEMM macros (4 waves 2x2 of 32x64) ==================
#define GEMM_PREAMBLE()                                                        \
    const int tid  = threadIdx.x;                                              \
    const int lane = tid & 63;                                                 \
    const int w    = tid >> 6;                                                 \
    const int wr   = w >> 1, wc = w & 1;                                       \
    const int m0   = blockIdx.y * 64;                                          \
    const int n0   = blockIdx.x * 128;                                         \
    const int fr   = lane & 15, fq = lane >> 4;                                \
    const int arow = tid >> 2, aseg = (tid & 3) * 8;                           \
    const int brow = tid >> 1, bseg = (tid & 1) * 16;                          \
    const bool a_ok = (m0 + arow) < M;                                         \
    const bool b_ok = (n0 + brow) < N;                                         \
    const float*          aptr  = A  + (size_t)(m0 + arow)*K + aseg;           \
    const float*          aptr2 = A2 ? A2 + (size_t)(m0 + arow)*K + aseg : (const float*)0; \
    const unsigned short* bptr  = WT + (size_t)(n0 + brow)*K + bseg;           \
    f32x4 acc[2][4];                                                           \
    _Pragma("unroll") for (int m = 0; m < 2; ++m)                              \
        _Pragma("unroll") for (int n = 0; n < 4; ++n)                          \
            acc[m][n] = (f32x4){0.f, 0.f, 0.f, 0.f};                           \
    float4 avA0, avB0, avA1, avB1;                                             \
    ushort8_t bvA0, bvB0, bvA1, bvB1;

#define GEMM_LOAD(avA, avB, bvA, bvB, kk) do {                                 \
    if (a_ok) {                                                                \
        avA = *(const float4*)(aptr + (kk));                                   \
        avB = *(const float4*)(aptr + (kk) + 4);                               \
        if (aptr2) {                                                           \
            float4 x2 = *(const float4*)(aptr2 + (kk));                        \
            float4 y2 = *(const float4*)(aptr2 + (kk) + 4);                    \
            avA.x += x2.x; avA.y += x2.y; avA.z += x2.z; avA.w += x2.w;        \
            avB.x += y2.x; avB.y += y2.y; avB.z += y2.z; avB.w += y2.w;        \
        }                                                                      \
    } else { avA = (float4){0,0,0,0}; avB = (float4){0,0,0,0}; }               \
    if (b_ok) { bvA = *(const ushort8_t*)(bptr + (kk));                        \
                bvB = *(const ushort8_t*)(bptr + (kk) + 8); }                  \
    else { _Pragma("unroll") for (int j = 0; j < 8; ++j){bvA[j]=0;bvB[j]=0;} } \
} while (0)

#define GEMM_STORE_LDS(avA, avB, bvA, bvB) do {                                \
    ushort8_t ac;                                                              \
    ac[0]=f2b(avA.x); ac[1]=f2b(avA.y); ac[2]=f2b(avA.z); ac[3]=f2b(avA.w);    \
    ac[4]=f2b(avB.x); ac[5]=f2b(avB.y); ac[6]=f2b(avB.z); ac[7]=f2b(avB.w);    \
    *(ushort8_t*)&As[arow][aseg]     = ac;                                     \
    *(ushort8_t*)&Bs[brow][bseg]     = bvA;                                    \
    *(ushort8_t*)&Bs[brow][bseg + 8] = bvB;                                    \
} while (0)

#define GEMM_COMPUTE() do {                                                    \
    bf16x8 af[2], bfv[4];                                                      \
    _Pragma("unroll") for (int m = 0; m < 2; ++m)                              \
        af[m] = *(const bf16x8*)&As[wr*32 + m*16 + fr][fq*8];                  \
    _Pragma("unroll") for (int n = 0; n < 4; ++n)                              \
        bfv[n] = *(const bf16x8*)&Bs[wc*64 + n*16 + fr][fq*8];                 \
    _Pragma("unroll") for (int m = 0; m < 2; ++m)                              \
        _Pragma("unroll") for (int n = 0; n < 4; ++n)                          \
            acc[m][n] = __builtin_amdgcn_mfma_f32_16x16x32_bf16(               \
                af[m], bfv[n], acc[m][n], 0, 0, 0);                            \
} while (0)

#define GEMM_KLOOP()                                                           \
    GEMM_LOAD(avA0, avB0, bvA0, bvB0, 0);                                      \
    for (int k0 = 0; k0 < K; k0 += 64) {                                       \
        __syncthreads();                                                       \
        GEMM_STORE_LDS(avA0, avB0, bvA0, bvB0);                                \
        GEMM_LOAD(avA1, avB1, bvA1, bvB1, k0 + 32);                            \
        __syncthreads();                                                       \
        GEMM_COMPUTE();                                                        \
        __syncthreads();                                                       \
        GEMM_STORE_LDS(avA1, avB1, bvA1, bvB1);                                \
        if (k0 + 64 < K) GEMM_LOAD(avA0, avB0, bvA0, bvB0, k0 + 64);           \
        __syncthreads();                                                       \
        GEMM_COMPUTE();                                                        \
    }

// ---------------- generic GEMM: C = (A [+A2]) @ WT^T + bias, opt relu --------
__global__ __launch_bounds__(256) void gemm_mfma64(
    const float* __restrict__ A, const float* __restrict__ A2,
    const unsigned short* __restrict__ WT,
    const float* __restrict__ bias, float* __restrict__ C,
    int M, int N, int K, int relu)
{
    __shared__ unsigned short As[64][40];
    __shared__ unsigned short Bs[128][40];
    GEMM_PREAMBLE();
    GEMM_KLOOP();

    #pragma unroll
    for (int n = 0; n < 4; ++n) {
        int col = n0 + wc*64 + n*16 + fr;
        if (col < N) {
            float bcol = bias[col];
            #pragma unroll
            for (int m = 0; m < 2; ++m) {
                int rbase = m0 + wr*32 + m*16 + fq*4;
                #pragma unroll
                for (int r = 0; r < 4; ++r) {
                    int row = rbase + r;
                    if (row < M) {
                        float vv = acc[m][n][r] + bcol;
                        if (relu) vv = fmaxf(vv, 0.f);
                        C[(size_t)row * N + col] = vv;
                    }
                }
            }
        }
    }
}

// ---------------- stage1: val (whole-N 64x256, 51KB LDS) + QK + V ------------
// blocks 0..2099: value GEMM -> bf16 head-major; 2100..2399: QK; 2400..2549: V.
__global__ __launch_bounds__(256) void stage1_kernel(
    const float* __restrict__ ehs, const float* __restrict__ h_in,
    const float* __restrict__ pos,
    const unsigned short* __restrict__ wtval, const float* __restrict__ b_val,
    unsigned short* __restrict__ val_bf,
    const unsigned short* __restrict__ wtqk, const float* __restrict__ bqk,
    float* __restrict__ buf_qk,
    const unsigned short* __restrict__ wtv, const float* __restrict__ bv,
    float* __restrict__ buf_v)
{
    __shared__ unsigned short LDS[25600];   // 51.2 KB -> 3 blocks/CU

    const int bid  = blockIdx.x;
    const int tid  = threadIdx.x;
    const int lane = tid & 63;
    const int w    = tid >> 6;
    const int wr   = w >> 1, wc = w & 1;
    const int fr   = lane & 15, fq = lane >> 4;

    if (bid < 2100) {
        // ------- value path: 64 rows x 256 cols, K chunks of 64 -------
        unsigned short (&As2)[2][64][40]  = *(unsigned short(*)[2][64][40])(LDS);
        unsigned short (&Bs2)[2][256][40] = *(unsigned short(*)[2][256][40])(LDS + 5120);
        const int m0 = bid * 64;

        f32x4 acc[2][8];
        #pragma unroll
        for (int m = 0; m < 2; ++m)
            #pragma unroll
            for (int n = 0; n < 8; ++n)
                acc[m][n] = (f32x4){0.f, 0.f, 0.f, 0.f};

        for (int kc = 0; kc < 4; ++kc) {
            const int kbase = kc * 64;
            __syncthreads();
            // stage A chunk: 64x64 fp32 -> bf16 (2 units/thread)
            #pragma unroll
            for (int i = 0; i < 2; ++i) {
                int uf = i*256 + tid;              // 0..511
                int row = uf >> 3, j = uf & 7;
                const float* src = ehs + (size_t)(m0 + row)*256 + kbase + j*8;
                float4 x = *(const float4*)src;
                float4 y = *(const float4*)(src + 4);
                ushort8_t u;
                u[0]=f2b(x.x); u[1]=f2b(x.y); u[2]=f2b(x.z); u[3]=f2b(x.w);
                u[4]=f2b(y.x); u[5]=f2b(y.y); u[6]=f2b(y.z); u[7]=f2b(y.w);
                *(ushort8_t*)&As2[j>>2][row][(j&3)*8] = u;
            }
            // stage B chunk: 256x64 bf16 (8 units/thread)
            #pragma unroll
            for (int i = 0; i < 8; ++i) {
                int uf = i*256 + tid;              // 0..2047
                int row = uf >> 3, j = uf & 7;
                ushort8_t u = *(const ushort8_t*)(wtval + (size_t)row*256 + kbase + j*8);
                *(ushort8_t*)&Bs2[j>>2][row][(j&3)*8] = u;
            }
            __syncthreads();
            // compute: 2 k-steps x 16 MFMA
            #pragma unroll
            for (int ks = 0; ks < 2; ++ks) {
                bf16x8 af[2], bfv[8];
                #pragma unroll
                for (int m = 0; m < 2; ++m)
                    af[m] = *(const bf16x8*)&As2[ks][wr*32 + m*16 + fr][fq*8];
                #pragma unroll
                for (int n = 0; n < 8; ++n)
                    bfv[n] = *(const bf16x8*)&Bs2[ks][wc*128 + n*16 + fr][fq*8];
                #pragma unroll
                for (int m = 0; m < 2; ++m)
                    #pragma unroll
                    for (int n = 0; n < 8; ++n)
                        acc[m][n] = __builtin_amdgcn_mfma_f32_16x16x32_bf16(
                            af[m], bfv[n], acc[m][n], 0, 0, 0);
            }
        }

        // epilogue: bias + bf16 head-major store
        #pragma unroll
        for (int n = 0; n < 8; ++n) {
            int col = wc*128 + n*16 + fr;          // 0..255
            int hh = col >> 5, dd = col & 31;
            float bcol = b_val[col];
            #pragma unroll
            for (int m = 0; m < 2; ++m) {
                int rbase = m0 + wr*32 + m*16 + fq*4;
                #pragma unroll
                for (int r = 0; r < 4; ++r) {
                    unsigned row = rbase + r;      // 0..134399
                    unsigned bb = row / (unsigned)S_;
                    unsigned ss = row - bb * (unsigned)S_;
                    val_bf[((size_t)(bb*NH_ + hh)*S_ + ss)*DH_ + dd] = f2b(acc[m][n][r] + bcol);
                }
            }
        }
    } else {
        // ------- qkv path: 64x128 tile, proven 2-barrier K-loop -------
        unsigned short (&As)[64][40]  = *(unsigned short(*)[64][40])(LDS);
        unsigned short (&Bs)[128][40] = *(unsigned short(*)[128][40])(LDS + 2560);

        const int t = bid - 2100;
        int m0, n0, Ncols;
        const float* A2p = nullptr;
        const unsigned short* Bp; const float* bias; float* C;
        if (t < 300) {
            m0 = (t >> 2)*64; n0 = (t & 3)*128;
            A2p = pos; Bp = wtqk; bias = bqk; C = buf_qk; Ncols = 512;
        } else {
            int tt = t - 300;
            m0 = (tt >> 1)*64; n0 = (tt & 1)*128;
            Bp = wtv; bias = bv; C = buf_v; Ncols = 256;
        }

        const int arow = tid >> 2, aseg = (tid & 3) * 8;
        const int brow = tid >> 1, bseg = (tid & 1) * 16;
        const bool a_ok = true, b_ok = true;
        const int K = 256;
        const float*          aptr  = h_in + (size_t)(m0 + arow)*256 + aseg;
        const float*          aptr2 = A2p ? A2p + (size_t)(m0 + arow)*256 + aseg : (const float*)0;
        const unsigned short* bptr  = Bp + (size_t)(n0 + brow)*256 + bseg;

        f32x4 acc[2][4];
        #pragma unroll
        for (int m = 0; m < 2; ++m)
            #pragma unroll
            for (int n = 0; n < 4; ++n)
                acc[m][n] = (f32x4){0.f, 0.f, 0.f, 0.f};
        float4 avA0, avB0, avA1, avB1;
        ushort8_t bvA0, bvB0, bvA1, bvB1;

        GEMM_KLOOP();

        #pragma unroll
        for (int n = 0; n < 4; ++n) {
            int col = n0 + wc*64 + n*16 + fr;
            float bcol = bias[col];
            #pragma unroll
            for (int m = 0; m < 2; ++m) {
                int rbase = m0 + wr*32 + m*16 + fq*4;
                #pragma unroll
                for (int r = 0; r < 4; ++r)
                    C[(size_t)(rbase + r) * Ncols + col] = acc[m][n][r] + bcol;
            }
        }
    }
}

// ---------------- fc1: GEMM + bias + relu -> bf16 out (exact shapes) ---------
__global__ __launch_bounds__(256) void gemm_relu_bf16(
    const float* __restrict__ A, const unsigned short* __restrict__ WT,
    const float* __restrict__ bias, unsigned short* __restrict__ OUT,
    int M, int N, int K)
{
    __shared__ unsigned short As[64][40];
    __shared__ unsigned short Bs[128][40];
    const float* A2 = nullptr;
    GEMM_PREAMBLE();
    GEMM_KLOOP();

    #pragma unroll
    for (int n = 0; n < 4; ++n) {
        int col = n0 + wc*64 + n*16 + fr;
        float bcol = bias[col];
        #pragma unroll
        for (int m = 0; m < 2; ++m) {
            int rbase = m0 + wr*32 + m*16 + fq*4;
            #pragma unroll
            for (int r = 0; r < 4; ++r)
                OUT[(size_t)(rbase + r) * N + col] = f2b(fmaxf(acc[m][n][r] + bcol, 0.f));
        }
    }
}

// ================= fused GEMM(N=256) + residual add + LayerNorm ==============
#define GLN16_COMPUTE() do {                                                   \
    bf16x8 af = *(const bf16x8*)&As[fr][fq*8];                                 \
    _Pragma("unroll") for (int n = 0; n < 4; ++n) {                            \
        bf16x8 bfv = *(const bf16x8*)&Bs[w*64 + n*16 + fr][fq*8];              \
        acc[n] = __builtin_amdgcn_mfma_f32_16x16x32_bf16(af, bfv, acc[n], 0, 0, 0); \
    }                                                                          \
} while (0)

#define GLN16_EPILOGUE()                                                       \
    float gcol[4], bcol2[4], biascol[4];                                       \
    _Pragma("unroll") for (int n = 0; n < 4; ++n) {                            \
        int col = w*64 + n*16 + fr;                                            \
        biascol[n] = bias[col]; gcol[n] = g[col]; bcol2[n] = bb[col];          \
    }                                                                          \
    _Pragma("unroll") for (int r = 0; r < 4; ++r) {                            \
        int row = fq*4 + r;                                                    \
        float s = 0.f, sq = 0.f;                                               \
        _Pragma("unroll") for (int n = 0; n < 4; ++n) {                        \
            int col = w*64 + n*16 + fr;                                        \
            float vv = acc[n][r] + biascol[n]                                  \
                     + X[(size_t)(m0 + row)*256 + col];                        \
            acc[n][r] = vv; s += vv; sq += vv*vv;                              \
        }                                                                      \
        s  += __shfl_xor(s, 1);  sq += __shfl_xor(sq, 1);                      \
        s  += __shfl_xor(s, 2);  sq += __shfl_xor(sq, 2);                      \
        s  += __shfl_xor(s, 4);  sq += __shfl_xor(sq, 4);                      \
        s  += __shfl_xor(s, 8);  sq += __shfl_xor(sq, 8);                      \
        if (fr == 0) { psum[row][w] = s; psq[row][w] = sq; }                   \
    }                                                                          \
    __syncthreads();                                                           \
    _Pragma("unroll") for (int r = 0; r < 4; ++r) {                            \
        int row = fq*4 + r;                                                    \
        float mean = (psum[row][0]+psum[row][1]+psum[row][2]+psum[row][3]) * (1.0f/256.0f); \
        float ex2  = (psq[row][0]+psq[row][1]+psq[row][2]+psq[row][3]) * (1.0f/256.0f);     \
        float rstd = rsqrtf(ex2 - mean*mean + 1e-5f);                          \
        _Pragma("unroll") for (int n = 0; n < 4; ++n) {                        \
            int col = w*64 + n*16 + fr;                                        \
            OUT[(size_t)(m0 + row)*256 + col] =                                \
                (acc[n][r] - mean)*rstd*gcol[n] + bcol2[n];                    \
        }                                                                      \
    }

__global__ __launch_bounds__(256) void gemm_ln_f32A(
    const float* __restrict__ A, const unsigned short* __restrict__ WT,
    const float* __restrict__ bias, const float* __restrict__ X,
    const float* __restrict__ g, const float* __restrict__ bb,
    float* __restrict__ OUT, int K)
{
    __shared__ unsigned short As[16][40];
    __shared__ unsigned short Bs[256][40];
    __shared__ float psum[16][4], psq[16][4];

    const int tid  = threadIdx.x;
    const int lane = tid & 63;
    const int w    = tid >> 6;
    const int m0   = blockIdx.x * 16;
    const int fr   = lane & 15, fq = lane >> 4;
    const bool astage = tid < 64;
    const int arow = (tid >> 2) & 15, aseg = (tid & 3) * 8;
    const float*          aptr = A  + (size_t)(m0 + arow)*K + aseg;
    const unsigned short* bptr = WT + (size_t)tid*K;

    f32x4 acc[4];
    #pragma unroll
    for (int n = 0; n < 4; ++n) acc[n] = (f32x4){0.f, 0.f, 0.f, 0.f};

    float4 a0x = {0,0,0,0}, a0y = {0,0,0,0}, a1x = {0,0,0,0}, a1y = {0,0,0,0};
    ushort8_t b0[4], b1[4];

    if (astage) { a0x = *(const float4*)(aptr); a0y = *(const float4*)(aptr + 4); }
    #pragma unroll
    for (int j = 0; j < 4; ++j) b0[j] = *(const ushort8_t*)(bptr + j*8);
    for (int k0 = 0; k0 < K; k0 += 64) {
        __syncthreads();
        if (astage) {
            ushort8_t ac;
            ac[0]=f2b(a0x.x); ac[1]=f2b(a0x.y); ac[2]=f2b(a0x.z); ac[3]=f2b(a0x.w);
            ac[4]=f2b(a0y.x); ac[5]=f2b(a0y.y); ac[6]=f2b(a0y.z); ac[7]=f2b(a0y.w);
            *(ushort8_t*)&As[arow][aseg] = ac;
        }
        #pragma unroll
        for (int j = 0; j < 4; ++j) *(ushort8_t*)&Bs[tid][j*8] = b0[j];
        if (astage) { a1x = *(const float4*)(aptr + k0 + 32); a1y = *(const float4*)(aptr + k0 + 36); }
        #pragma unroll
        for (int j = 0; j < 4; ++j) b1[j] = *(const ushort8_t*)(bptr + k0 + 32 + j*8);
        __syncthreads();
        GLN16_COMPUTE();
        __syncthreads();
        if (astage) {
            ushort8_t ac;
            ac[0]=f2b(a1x.x); ac[1]=f2b(a1x.y); ac[2]=f2b(a1x.z); ac[3]=f2b(a1x.w);
            ac[4]=f2b(a1y.x); ac[5]=f2b(a1y.y); ac[6]=f2b(a1y.z); ac[7]=f2b(a1y.w);
            *(ushort8_t*)&As[arow][aseg] = ac;
        }
        #pragma unroll
        for (int j = 0; j < 4; ++j) *(ushort8_t*)&Bs[tid][j*8] = b1[j];
        if (k0 + 64 < K) {
            if (astage) { a0x = *(const float4*)(aptr + k0 + 64); a0y = *(const float4*)(aptr + k0 + 68); }
            #pragma unroll
            for (int j = 0; j < 4; ++j) b0[j] = *(const ushort8_t*)(bptr + k0 + 64 + j*8);
        }
        __syncthreads();
        GLN16_COMPUTE();
    }

    GLN16_EPILOGUE();
}

__global__ __launch_bounds__(256) void gemm_ln_bf16A(
    const unsigned short* __restrict__ A, const unsigned short* __restrict__ WT,
    const float* __restrict__ bias, const float* __restrict__ X,
    const float* __restrict__ g, const float* __restrict__ bb,
    float* __restrict__ OUT, int K)
{
    __shared__ unsigned short As[16][40];
    __shared__ unsigned short Bs[256][40];
    __shared__ float psum[16][4], psq[16][4];

    const int tid  = threadIdx.x;
    const int lane = tid & 63;
    const int w    = tid >> 6;
    const int m0   = blockIdx.x * 16;
    const int fr   = lane & 15, fq = lane >> 4;
    const bool astage = tid < 64;
    const int arow = (tid >> 2) & 15, aseg = (tid & 3) * 8;
    const unsigned short* aptr = A  + (size_t)(m0 + arow)*K + aseg;
    const unsigned short* bptr = WT + (size_t)tid*K;

    f32x4 acc[4];
    #pragma unroll
    for (int n = 0; n < 4; ++n) acc[n] = (f32x4){0.f, 0.f, 0.f, 0.f};

    ushort8_t a0, a1, b0[4], b1[4];
    #pragma unroll
    for (int j = 0; j < 8; ++j) { a0[j] = 0; a1[j] = 0; }

    if (astage) a0 = *(const ushort8_t*)(aptr);
    #pragma unroll
    for (int j = 0; j < 4; ++j) b0[j] = *(const ushort8_t*)(bptr + j*8);
    for (int k0 = 0; k0 < K; k0 += 64) {
        __syncthreads();
        if (astage) *(ushort8_t*)&As[arow][aseg] = a0;
        #pragma unroll
        for (int j = 0; j < 4; ++j) *(ushort8_t*)&Bs[tid][j*8] = b0[j];
        if (astage) a1 = *(const ushort8_t*)(aptr + k0 + 32);
        #pragma unroll
        for (int j = 0; j < 4; ++j) b1[j] = *(const ushort8_t*)(bptr + k0 + 32 + j*8);
        __syncthreads();
        GLN16_COMPUTE();
        __syncthreads();
        if (astage) *(ushort8_t*)&As[arow][aseg] = a1;
        #pragma unroll
        for (int j = 0; j < 4; ++j) *(ushort8_t*)&Bs[tid][j*8] = b1[j];
        if (k0 + 64 < K) {
            if (astage) a0 = *(const ushort8_t*)(aptr + k0 + 64);
            #pragma unroll
            for (int j = 0; j < 4; ++j) b0[j] = *(const ushort8_t*)(bptr + k0 + 64 + j*8);
        }
        __syncthreads();
        GLN16_COMPUTE();
    }

    GLN16_EPILOGUE();
}

// ---------------- self attention via MFMA ----------------
__global__ __launch_bounds__(256) void self_attn_kernel(
    const float* __restrict__ qk, const float* __restrict__ v,
    float* __restrict__ sa)
{
    __shared__ unsigned short k_sw[304*32];      // K bf16, 16B-unit XOR swizzled
    __shared__ unsigned short vt[32][312];       // V^T bf16: [d][key]
    __shared__ unsigned short p_all[4][16][312]; // per-wave P: [q_local][key]

    const int bid  = blockIdx.x;
    const int part = bid % 5;
    const int bh   = bid / 5;
    const int h    = bh & 7;
    const int b    = bh >> 3;
    const int tid  = threadIdx.x;
    const int lane = tid & 63;
    const int w    = tid >> 6;
    const int g    = lane >> 4;   // 0..3
    const int fr   = lane & 15;

    const size_t qbase = (size_t)b*NQ_*512 + h*DH_;
    const size_t kbase = qbase + 256;
    const size_t vbase = (size_t)b*NQ_*D_ + h*DH_;
    const size_t sbase = (size_t)b*NQ_*D_ + h*DH_;

    for (int i = tid; i < 1216; i += 256) {
        int r = i >> 2, u = i & 3;
        ushort8_t kb;
        if (r < NQ_) {
            const float* p8 = qk + kbase + (size_t)r*512 + u*8;
            float4 a0 = *(const float4*)p8;
            float4 a1 = *(const float4*)(p8 + 4);
            kb[0]=f2b(a0.x); kb[1]=f2b(a0.y); kb[2]=f2b(a0.z); kb[3]=f2b(a0.w);
            kb[4]=f2b(a1.x); kb[5]=f2b(a1.y); kb[6]=f2b(a1.z); kb[7]=f2b(a1.w);
        } else {
            #pragma unroll
            for (int j = 0; j < 8; ++j) kb[j] = 0;
        }
        int su = u ^ ((r >> 1) & 3);
        *(ushort8_t*)&k_sw[r*32 + su*8] = kb;
    }
    for (int i = tid; i < 1216; i += 256) {
        int kk = i >> 2, u = i & 3;
        if (kk < NQ_) {
            const float* p8 = v + vbase + (size_t)kk*D_ + u*8;
            float4 a0 = *(const float4*)p8;
            float4 a1 = *(const float4*)(p8 + 4);
            float f[8] = {a0.x,a0.y,a0.z,a0.w,a1.x,a1.y,a1.z,a1.w};
            #pragma unroll
            for (int j = 0; j < 8; ++j) vt[u*8 + j][kk] = f2b(f[j]);
        } else {
            #pragma unroll
            for (int j = 0; j < 8; ++j) vt[u*8 + j][kk] = 0;
        }
    }
    __syncthreads();

    const int q0 = part*64 + w*16;
    const int qi = q0 + fr;
    bf16x8 qf;
    if (qi < NQ_) {
        const float scale = 0.17677669529663687f;
        const float* p8 = qk + qbase + (size_t)qi*512 + g*8;
        float4 a0 = *(const float4*)p8;
        float4 a1 = *(const float4*)(p8 + 4);
        qf[0]=(short)f2b(a0.x*scale); qf[1]=(short)f2b(a0.y*scale);
        qf[2]=(short)f2b(a0.z*scale); qf[3]=(short)f2b(a0.w*scale);
        qf[4]=(short)f2b(a1.x*scale); qf[5]=(short)f2b(a1.y*scale);
        qf[6]=(short)f2b(a1.z*scale); qf[7]=(short)f2b(a1.w*scale);
    } else {
        #pragma unroll
        for (int j = 0; j < 8; ++j) qf[j] = 0;
    }

    const int ksw_u = g ^ ((fr >> 1) & 3);
    f32x4 acc[19];
    #pragma unroll
    for (int t = 0; t < 19; ++t) acc[t] = (f32x4){0.f,0.f,0.f,0.f};
    #pragma unroll
    for (int t = 0; t < 19; ++t) {
        int row = t*16 + fr;
        bf16x8 kf = *(const bf16x8*)&k_sw[row*32 + ksw_u*8];
        acc[t] = __builtin_amdgcn_mfma_f32_16x16x32_bf16(kf, qf, acc[t], 0, 0, 0);
    }
    if (g == 3) acc[18] = (f32x4){-1e30f, -1e30f, -1e30f, -1e30f};

    float m = -1e30f;
    #pragma unroll
    for (int t = 0; t < 19; ++t) {
        #pragma unroll
        for (int r = 0; r < 4; ++r) m = fmaxf(m, acc[t][r]);
    }
    m = fmaxf(m, __shfl_xor(m, 16));
    m = fmaxf(m, __shfl_xor(m, 32));
    float lsum = 0.f;
    #pragma unroll
    for (int t = 0; t < 19; ++t) {
        #pragma unroll
        for (int r = 0; r < 4; ++r) {
            float e = __expf(acc[t][r] - m);
            acc[t][r] = e;
            lsum += e;
        }
    }
    lsum += __shfl_xor(lsum, 16);
    lsum += __shfl_xor(lsum, 32);
    float inv = 1.0f / lsum;

    #pragma unroll
    for (int t = 0; t < 19; ++t) {
        ushort4_t pw = { f2b(acc[t][0]*inv), f2b(acc[t][1]*inv),
                         f2b(acc[t][2]*inv), f2b(acc[t][3]*inv) };
        *(ushort4_t*)&p_all[w][fr][t*16 + g*4] = pw;
    }

    f32x4 o0 = (f32x4){0.f,0.f,0.f,0.f};
    f32x4 o1 = (f32x4){0.f,0.f,0.f,0.f};
    #pragma unroll
    for (int ks = 0; ks < 10; ++ks) {
        int kb = ks*32 + g*8;
        bf16x8 pf, vf0, vf1;
        if (kb < 304) {
            pf  = *(const bf16x8*)&p_all[w][fr][kb];
            vf0 = *(const bf16x8*)&vt[fr][kb];
            vf1 = *(const bf16x8*)&vt[16 + fr][kb];
        } else {
            #pragma unroll
            for (int j = 0; j < 8; ++j) { pf[j] = 0; vf0[j] = 0; vf1[j] = 0; }
        }
        o0 = __builtin_amdgcn_mfma_f32_16x16x32_bf16(pf, vf0, o0, 0, 0, 0);
        o1 = __builtin_amdgcn_mfma_f32_16x16x32_bf16(pf, vf1, o1, 0, 0, 0);
    }

    #pragma unroll
    for (int r = 0; r < 4; ++r) {
        int qo = q0 + g*4 + r;
        if (qo < NQ_) {
            sa[sbase + (size_t)qo*D_ + fr]      = o0[r];
            sa[sbase + (size_t)qo*D_ + 16 + fr] = o1[r];
        }
    }
}

// ---------------- deformable bilinear sampling: 2 d's per thread -------------
__global__ __launch_bounds__(256) void deform_kernel(
    const unsigned short* __restrict__ value, const float* __restrict__ oa,
    const float* __restrict__ refp, float* __restrict__ dout)
{
    int gid = blockIdx.x*256 + threadIdx.x;
    int l16 = gid & 15;
    int grp = gid >> 4;            // (b*NQ+q)*8 + h
    int h = grp & 7;
    int bq = grp >> 3;
    int qq = bq % NQ_;
    int b  = bq / NQ_;
    int d0 = l16*2;

    const int starts[3] = {0, 6400, 8000};
    const int Hs[3] = {80, 40, 20};

    const float* offp = oa + (size_t)(b*NQ_+qq)*288 + h*24;
    const float* awp  = oa + (size_t)(b*NQ_+qq)*288 + 192 + h*12;
    const float* refq = refp + (size_t)(b*NQ_+qq)*(L_*2);
    const unsigned short* vb = value + ((size_t)(b*NH_ + h)*S_)*DH_ + d0;

    float av[12];
    float mx = -1e30f;
    #pragma unroll
    for (int i = 0; i < 12; ++i) { av[i] = awp[i]; mx = fmaxf(mx, av[i]); }
    float ssum = 0.f;
    #pragma unroll
    for (int i = 0; i < 12; ++i) { av[i] = __expf(av[i]-mx); ssum += av[i]; }
    float sinv = 1.f / ssum;

    float acc0 = 0.f, acc1 = 0.f;
    #pragma unroll
    for (int l = 0; l < L_; l++) {
        int Hl = Hs[l], Wl = Hs[l];
        float rx = refq[l*2+0], ry = refq[l*2+1];
        const unsigned short* vlb = vb + (size_t)starts[l]*DH_;
        #pragma unroll
        for (int p = 0; p < P_; p++) {
            float ox = offp[(l*P_+p)*2+0], oy = offp[(l*P_+p)*2+1];
            float a  = av[l*P_+p] * sinv;
            float x = (rx + ox/(float)Wl)*(float)Wl - 0.5f;
            float y = (ry + oy/(float)Hl)*(float)Hl - 0.5f;
            float x0 = floorf(x), y0 = floorf(y);
            #pragma unroll
            for (int dy = 0; dy < 2; dy++) {
                #pragma unroll
                for (int dx = 0; dx < 2; dx++) {
                    float xi = x0 + dx, yi = y0 + dy;
                    float wgt = (1.f - fabsf(x-xi))*(1.f - fabsf(y-yi));
                    bool valid = (xi >= 0.f) && (xi < (float)Wl) && (yi >= 0.f) && (yi < (float)Hl);
                    if (valid && wgt != 0.f) {
                        int ix = (int)xi, iy = (int)yi;
                        unsigned u = *(const unsigned*)(vlb + (size_t)(iy*Wl + ix)*DH_);
                        float aw2 = a * wgt;
                        acc0 += aw2 * b2f((unsigned short)(u & 0xffff));
                        acc1 += aw2 * b2f((unsigned short)(u >> 16));
                    }
                }
            }
        }
    }
    float2 o = { acc0, acc1 };
    *(float2*)&dout[(size_t)grp*32 + d0] = o;
}

// ---------------- launch ----------------
extern "C" void kernel_launch(void* const* d_in, const int* in_sizes, int n_in,
                              void* d_out, int out_size, void* d_ws, size_t ws_size,
                              hipStream_t stream) {
    (void)in_sizes; (void)n_in; (void)out_size; (void)ws_size;
    const float* h_in  = (const float*)d_in[0];
    const float* pos   = (const float*)d_in[1];
    const float* ehs   = (const float*)d_in[2];
    const float* refp  = (const float*)d_in[3];
    // d_in[4] = spatial_shapes (hardcoded)
    const float* wq    = (const float*)d_in[5];
    const float* bq    = (const float*)d_in[6];
    const float* wk    = (const float*)d_in[7];
    const float* bk    = (const float*)d_in[8];
    const float* wv    = (const float*)d_in[9];
    const float* bv    = (const float*)d_in[10];
    const float* wo    = (const float*)d_in[11];
    const float* bo    = (const float*)d_in[12];
    const float* ln1g  = (const float*)d_in[13];
    const float* ln1b  = (const float*)d_in[14];
    const float* w_off = (const float*)d_in[15];
    const float* b_off = (const float*)d_in[16];
    const float* w_aw  = (const float*)d_in[17];
    const float* b_aw  = (const float*)d_in[18];
    const float* w_val = (const float*)d_in[19];
    const float* b_val = (const float*)d_in[20];
    const float* w_out = (const float*)d_in[21];
    const float* b_out = (const float*)d_in[22];
    const float* ln2g  = (const float*)d_in[23];
    const float* ln2b  = (const float*)d_in[24];
    const float* w_fc1 = (const float*)d_in[25];
    const float* b_fc1 = (const float*)d_in[26];
    const float* w_fc2 = (const float*)d_in[27];
    const float* b_fc2 = (const float*)d_in[28];
    const float* ln3g  = (const float*)d_in[29];
    const float* ln3b  = (const float*)d_in[30];
    float* out = (float*)d_out;

    float* ws = (float*)d_ws;
    float* buf_qk   = ws + 1*(size_t)NB_;          // fused q|k, 4800x512 (2 NB)
    float* buf_v    = ws + 3*(size_t)NB_;          // v proj; later deform out
    float* buf_sa   = ws + 4*(size_t)NB_;          // sa
    float* buf_h1   = ws + 6*(size_t)NB_;
    float* buf_h2   = ws + 7*(size_t)NB_;
    float* buf_oa   = ws + 8*(size_t)NB_;          // fused off|aw (raw), 4800x288
    unsigned short* fc1_bf = (unsigned short*)(ws + 9*(size_t)NB_ + NB_/2);   // 4800x1024 bf16
    unsigned short* val_bf = (unsigned short*)(ws + 13*(size_t)NB_ + NB_/2);  // (14 NB)

    unsigned short* wtb = (unsigned short*)(ws + 27*(size_t)NB_ + NB_/2);
    unsigned short* wtqk  = wtb;                   // 512x256
    unsigned short* wtv   = wtqk  + 131072;        // 256x256
    unsigned short* wto   = wtv   + 65536;
    unsigned short* wtval = wto   + 65536;
    unsigned short* wtout = wtval + 65536;
    unsigned short* wtoa  = wtout + 65536;         // 288x256
    unsigned short* wtfc1 = wtoa  + 73728;         // 1024x256
    unsigned short* wtfc2 = wtfc1 + 262144;        // 256x1024
    float* bqk = (float*)(wtfc2 + 262144);         // 512
    float* boa = bqk + 512;                        // 288

    dim3 blk(256);

    // ---- fused weight prep (1 launch) ----
    prep_kernel<<<dim3(972), blk, 0, stream>>>(
        wq, wk, wv, wo, w_val, w_out, w_off, w_aw, w_fc1, w_fc2,
        bq, bk, b_off, b_aw,
        wtqk, wtv, wto, wtval, wtout, wtoa, wtfc1, wtfc2, bqk, boa);

    // ---- stage1: value (whole-N, 51KB LDS) + QK + V (1 launch, 2550 blocks) ----
    stage1_kernel<<<dim3(2550), blk, 0, stream>>>(
        ehs, h_in, pos, wtval, b_val, val_bf, wtqk, bqk, buf_qk, wtv, bv, buf_v);

    // self attention (MFMA)
    self_attn_kernel<<<dim3(B_*NH_*5), blk, 0, stream>>>(buf_qk, buf_v, buf_sa);
    // wo projection + residual + LN1 -> h1  (fused, 300 blocks)
    gemm_ln_f32A<<<dim3(ROWS_/16), blk, 0, stream>>>(
        buf_sa, wto, bo, h_in, ln1g, ln1b, buf_h1, 256);
    // fused offsets + attention weights (A2 = pos); aw stays RAW (softmax in deform)
    gemm_mfma64<<<dim3(3, 75), blk, 0, stream>>>(buf_h1, pos, wtoa, boa, buf_oa, ROWS_, 288, D_, 0);
    // deformable sampling (inline softmax, 2 d's/thread)
    deform_kernel<<<dim3(ROWS_*NH_*16/256), blk, 0, stream>>>(val_bf, buf_oa, refp, buf_v);
    // ca projection + residual + LN2 -> h2  (fused, 300 blocks)
    gemm_ln_f32A<<<dim3(ROWS_/16), blk, 0, stream>>>(
        buf_v, wtout, b_out, buf_h1, ln2g, ln2b, buf_h2, 256);
    // FFN: fc1 -> bf16, then fc2 + residual + LN3 -> out (fused, 300 blocks)
    gemm_relu_bf16<<<dim3(8, 75), blk, 0, stream>>>(buf_h2, wtfc1, b_fc1, fc1_bf, ROWS_, FFN_, D_);
    gemm_ln_bf16A<<<dim3(ROWS_/16), blk, 0, stream>>>(
        fc1_bf, wtfc2, b_fc2, buf_h2, ln3g, ln3b, out, FFN_);
}

// Round 17
// 192.821 us; speedup vs baseline: 1.1360x; 1.0914x over previous
//
#include <hip/hip_runtime.h>
#include <hip/hip_bf16.h>
#include <math.h>

// ---------------- problem constants ----------------
#define B_   16
#define NQ_  300
#define D_   256
#define NH_  8
#define DH_  32
#define L_   3
#define P_   4
#define FFN_ 1024
#define S_   8400   // 80*80 + 40*40 + 20*20
#define ROWS_ (B_*NQ_)        // 4800
#define NB_   (ROWS_*D_)      // 1228800 floats per (B,NQ,D) buffer

typedef __attribute__((ext_vector_type(4))) unsigned short ushort4_t;
typedef __attribute__((ext_vector_type(8))) unsigned short ushort8_t;
typedef __attribute__((ext_vector_type(8))) short bf16x8;
typedef __attribute__((ext_vector_type(4))) float f32x4;

__device__ inline unsigned short f2b(float f) {
    __hip_bfloat16 h = __float2bfloat16(f);
    return __builtin_bit_cast(unsigned short, h);
}
__device__ inline float b2f(unsigned short u) {
    union { unsigned u; float f; } c; c.u = ((unsigned)u) << 16; return c.f;
}

// ---------------- fused weight prep: 10 transposes + 2 bias concats ----------
__global__ __launch_bounds__(256) void prep_kernel(
    const float* __restrict__ wq, const float* __restrict__ wk,
    const float* __restrict__ wv, const float* __restrict__ wo,
    const float* __restrict__ w_val, const float* __restrict__ w_out,
    const float* __restrict__ w_off, const float* __restrict__ w_aw,
    const float* __restrict__ w_fc1, const float* __restrict__ w_fc2,
    const float* __restrict__ bq, const float* __restrict__ bk,
    const float* __restrict__ b_off, const float* __restrict__ b_aw,
    unsigned short* __restrict__ wtqk, unsigned short* __restrict__ wtv,
    unsigned short* __restrict__ wto, unsigned short* __restrict__ wtval,
    unsigned short* __restrict__ wtout, unsigned short* __restrict__ wtoa,
    unsigned short* __restrict__ wtfc1, unsigned short* __restrict__ wtfc2,
    float* __restrict__ bqk, float* __restrict__ boa)
{
    const int bid = blockIdx.x;
    if (bid >= 968) {
        int idx = (bid - 968)*256 + threadIdx.x;   // 0..1023
        if (idx < 512) bqk[idx] = (idx < 256) ? bq[idx] : bk[idx-256];
        else { int j = idx - 512; if (j < 288) boa[j] = (j < 192) ? b_off[j] : b_aw[j-192]; }
        return;
    }
    const float* src; unsigned short* dst; int K, N, t;
    if      (bid < 64)  { src=wq;    dst=wtqk;         K=256;  N=256;  t=bid; }
    else if (bid < 128) { src=wk;    dst=wtqk+65536;   K=256;  N=256;  t=bid-64; }
    else if (bid < 192) { src=wv;    dst=wtv;          K=256;  N=256;  t=bid-128; }
    else if (bid < 256) { src=wo;    dst=wto;          K=256;  N=256;  t=bid-192; }
    else if (bid < 320) { src=w_val; dst=wtval;        K=256;  N=256;  t=bid-256; }
    else if (bid < 384) { src=w_out; dst=wtout;        K=256;  N=256;  t=bid-320; }
    else if (bid < 432) { src=w_off; dst=wtoa;         K=256;  N=192;  t=bid-384; }
    else if (bid < 456) { src=w_aw;  dst=wtoa+49152;   K=256;  N=96;   t=bid-432; }
    else if (bid < 712) { src=w_fc1; dst=wtfc1;        K=256;  N=1024; t=bid-456; }
    else                { src=w_fc2; dst=wtfc2;        K=1024; N=256;  t=bid-712; }

    __shared__ unsigned short tl[32][33];
    int tid = threadIdx.x;
    int tx = tid & 31, ty = tid >> 5;           // ty 0..7
    int ntx = N >> 5;
    int n0 = (t % ntx) * 32, k0 = (t / ntx) * 32;
    #pragma unroll
    for (int i = 0; i < 4; ++i)
        tl[tx][ty + i*8] = f2b(src[(size_t)(k0 + ty + i*8)*N + n0 + tx]);
    __syncthreads();
    #pragma unroll
    for (int i = 0; i < 4; ++i)
        dst[(size_t)(n0 + ty + i*8)*K + k0 + tx] = tl[ty + i*8][tx];
}

// ================= 64x128 GEMM macros (4 waves 2x2 of 32x64) ==================
#define GEMM_PREAMBLE()                                                        \
    const int tid  = threadIdx.x;                                              \
    const int lane = tid & 63;                                                 \
    const int w    = tid >> 6;                                                 \
    const int wr   = w >> 1, wc = w & 1;                                       \
    const int m0   = blockIdx.y * 64;                                          \
    const int n0   = blockIdx.x * 128;                                         \
    const int fr   = lane & 15, fq = lane >> 4;                                \
    const int arow = tid >> 2, aseg = (tid & 3) * 8;                           \
    const int brow = tid >> 1, bseg = (tid & 1) * 16;                          \
    const bool a_ok = (m0 + arow) < M;                                         \
    const bool b_ok = (n0 + brow) < N;                                         \
    const float*          aptr  = A  + (size_t)(m0 + arow)*K + aseg;           \
    const float*          aptr2 = A2 ? A2 + (size_t)(m0 + arow)*K + aseg : (const float*)0; \
    const unsigned short* bptr  = WT + (size_t)(n0 + brow)*K + bseg;           \
    f32x4 acc[2][4];                                                           \
    _Pragma("unroll") for (int m = 0; m < 2; ++m)                              \
        _Pragma("unroll") for (int n = 0; n < 4; ++n)                          \
            acc[m][n] = (f32x4){0.f, 0.f, 0.f, 0.f};                           \
    float4 avA0, avB0, avA1, avB1;                                             \
    ushort8_t bvA0, bvB0, bvA1, bvB1;

#define GEMM_LOAD(avA, avB, bvA, bvB, kk) do {                                 \
    if (a_ok) {                                                                \
        avA = *(const float4*)(aptr + (kk));                                   \
        avB = *(const float4*)(aptr + (kk) + 4);                               \
        if (aptr2) {                                                           \
            float4 x2 = *(const float4*)(aptr2 + (kk));                        \
            float4 y2 = *(const float4*)(aptr2 + (kk) + 4);                    \
            avA.x += x2.x; avA.y += x2.y; avA.z += x2.z; avA.w += x2.w;        \
            avB.x += y2.x; avB.y += y2.y; avB.z += y2.z; avB.w += y2.w;        \
        }                                                                      \
    } else { avA = (float4){0,0,0,0}; avB = (float4){0,0,0,0}; }               \
    if (b_ok) { bvA = *(const ushort8_t*)(bptr + (kk));                        \
                bvB = *(const ushort8_t*)(bptr + (kk) + 8); }                  \
    else { _Pragma("unroll") for (int j = 0; j < 8; ++j){bvA[j]=0;bvB[j]=0;} } \
} while (0)

#define GEMM_STORE_LDS(avA, avB, bvA, bvB) do {                                \
    ushort8_t ac;                                                              \
    ac[0]=f2b(avA.x); ac[1]=f2b(avA.y); ac[2]=f2b(avA.z); ac[3]=f2b(avA.w);    \
    ac[4]=f2b(avB.x); ac[5]=f2b(avB.y); ac[6]=f2b(avB.z); ac[7]=f2b(avB.w);    \
    *(ushort8_t*)&As[arow][aseg]     = ac;                                     \
    *(ushort8_t*)&Bs[brow][bseg]     = bvA;                                    \
    *(ushort8_t*)&Bs[brow][bseg + 8] = bvB;                                    \
} while (0)

#define GEMM_COMPUTE() do {                                                    \
    bf16x8 af[2], bfv[4];                                                      \
    _Pragma("unroll") for (int m = 0; m < 2; ++m)                              \
        af[m] = *(const bf16x8*)&As[wr*32 + m*16 + fr][fq*8];                  \
    _Pragma("unroll") for (int n = 0; n < 4; ++n)                              \
        bfv[n] = *(const bf16x8*)&Bs[wc*64 + n*16 + fr][fq*8];                 \
    _Pragma("unroll") for (int m = 0; m < 2; ++m)                              \
        _Pragma("unroll") for (int n = 0; n < 4; ++n)                          \
            acc[m][n] = __builtin_amdgcn_mfma_f32_16x16x32_bf16(               \
                af[m], bfv[n], acc[m][n], 0, 0, 0);                            \
} while (0)

#define GEMM_KLOOP()                                                           \
    GEMM_LOAD(avA0, avB0, bvA0, bvB0, 0);                                      \
    for (int k0 = 0; k0 < K; k0 += 64) {                                       \
        __syncthreads();                                                       \
        GEMM_STORE_LDS(avA0, avB0, bvA0, bvB0);                                \
        GEMM_LOAD(avA1, avB1, bvA1, bvB1, k0 + 32);                            \
        __syncthreads();                                                       \
        GEMM_COMPUTE();                                                        \
        __syncthreads();                                                       \
        GEMM_STORE_LDS(avA1, avB1, bvA1, bvB1);                                \
        if (k0 + 64 < K) GEMM_LOAD(avA0, avB0, bvA0, bvB0, k0 + 64);           \
        __syncthreads();                                                       \
        GEMM_COMPUTE();                                                        \
    }

// ---------------- generic GEMM: C = (A [+A2]) @ WT^T + bias, opt relu --------
__global__ __launch_bounds__(256) void gemm_mfma64(
    const float* __restrict__ A, const float* __restrict__ A2,
    const unsigned short* __restrict__ WT,
    const float* __restrict__ bias, float* __restrict__ C,
    int M, int N, int K, int relu)
{
    __shared__ unsigned short As[64][40];
    __shared__ unsigned short Bs[128][40];
    GEMM_PREAMBLE();
    GEMM_KLOOP();

    #pragma unroll
    for (int n = 0; n < 4; ++n) {
        int col = n0 + wc*64 + n*16 + fr;
        if (col < N) {
            float bcol = bias[col];
            #pragma unroll
            for (int m = 0; m < 2; ++m) {
                int rbase = m0 + wr*32 + m*16 + fq*4;
                #pragma unroll
                for (int r = 0; r < 4; ++r) {
                    int row = rbase + r;
                    if (row < M) {
                        float vv = acc[m][n][r] + bcol;
                        if (relu) vv = fmaxf(vv, 0.f);
                        C[(size_t)row * N + col] = vv;
                    }
                }
            }
        }
    }
}

// ---------------- stage1: val (whole-N 64x256, 51KB LDS) + QK + V ------------
// blocks 0..2099: value GEMM -> bf16 head-major; 2100..2399: QK (bf16 out);
// 2400..2549: V (bf16 out).
__global__ __launch_bounds__(256) void stage1_kernel(
    const float* __restrict__ ehs, const float* __restrict__ h_in,
    const float* __restrict__ pos,
    const unsigned short* __restrict__ wtval, const float* __restrict__ b_val,
    unsigned short* __restrict__ val_bf,
    const unsigned short* __restrict__ wtqk, const float* __restrict__ bqk,
    unsigned short* __restrict__ qk_bf,
    const unsigned short* __restrict__ wtv, const float* __restrict__ bv,
    unsigned short* __restrict__ v_bf)
{
    __shared__ unsigned short LDS[25600];   // 51.2 KB -> 3 blocks/CU

    const int bid  = blockIdx.x;
    const int tid  = threadIdx.x;
    const int lane = tid & 63;
    const int w    = tid >> 6;
    const int wr   = w >> 1, wc = w & 1;
    const int fr   = lane & 15, fq = lane >> 4;

    if (bid < 2100) {
        // ------- value path: 64 rows x 256 cols, K chunks of 64 -------
        unsigned short (&As2)[2][64][40]  = *(unsigned short(*)[2][64][40])(LDS);
        unsigned short (&Bs2)[2][256][40] = *(unsigned short(*)[2][256][40])(LDS + 5120);
        const int m0 = bid * 64;

        f32x4 acc[2][8];
        #pragma unroll
        for (int m = 0; m < 2; ++m)
            #pragma unroll
            for (int n = 0; n < 8; ++n)
                acc[m][n] = (f32x4){0.f, 0.f, 0.f, 0.f};

        for (int kc = 0; kc < 4; ++kc) {
            const int kbase = kc * 64;
            __syncthreads();
            // stage A chunk: 64x64 fp32 -> bf16 (2 units/thread)
            #pragma unroll
            for (int i = 0; i < 2; ++i) {
                int uf = i*256 + tid;              // 0..511
                int row = uf >> 3, j = uf & 7;
                const float* src = ehs + (size_t)(m0 + row)*256 + kbase + j*8;
                float4 x = *(const float4*)src;
                float4 y = *(const float4*)(src + 4);
                ushort8_t u;
                u[0]=f2b(x.x); u[1]=f2b(x.y); u[2]=f2b(x.z); u[3]=f2b(x.w);
                u[4]=f2b(y.x); u[5]=f2b(y.y); u[6]=f2b(y.z); u[7]=f2b(y.w);
                *(ushort8_t*)&As2[j>>2][row][(j&3)*8] = u;
            }
            // stage B chunk: 256x64 bf16 (8 units/thread)
            #pragma unroll
            for (int i = 0; i < 8; ++i) {
                int uf = i*256 + tid;              // 0..2047
                int row = uf >> 3, j = uf & 7;
                ushort8_t u = *(const ushort8_t*)(wtval + (size_t)row*256 + kbase + j*8);
                *(ushort8_t*)&Bs2[j>>2][row][(j&3)*8] = u;
            }
            __syncthreads();
            // compute: 2 k-steps x 16 MFMA
            #pragma unroll
            for (int ks = 0; ks < 2; ++ks) {
                bf16x8 af[2], bfv[8];
                #pragma unroll
                for (int m = 0; m < 2; ++m)
                    af[m] = *(const bf16x8*)&As2[ks][wr*32 + m*16 + fr][fq*8];
                #pragma unroll
                for (int n = 0; n < 8; ++n)
                    bfv[n] = *(const bf16x8*)&Bs2[ks][wc*128 + n*16 + fr][fq*8];
                #pragma unroll
                for (int m = 0; m < 2; ++m)
                    #pragma unroll
                    for (int n = 0; n < 8; ++n)
                        acc[m][n] = __builtin_amdgcn_mfma_f32_16x16x32_bf16(
                            af[m], bfv[n], acc[m][n], 0, 0, 0);
            }
        }

        // epilogue: bias + bf16 head-major store
        #pragma unroll
        for (int n = 0; n < 8; ++n) {
            int col = wc*128 + n*16 + fr;          // 0..255
            int hh = col >> 5, dd = col & 31;
            float bcol = b_val[col];
            #pragma unroll
            for (int m = 0; m < 2; ++m) {
                int rbase = m0 + wr*32 + m*16 + fq*4;
                #pragma unroll
                for (int r = 0; r < 4; ++r) {
                    unsigned row = rbase + r;      // 0..134399
                    unsigned bb = row / (unsigned)S_;
                    unsigned ss = row - bb * (unsigned)S_;
                    val_bf[((size_t)(bb*NH_ + hh)*S_ + ss)*DH_ + dd] = f2b(acc[m][n][r] + bcol);
                }
            }
        }
    } else {
        // ------- qkv path: 64x128 tile, proven 2-barrier K-loop, bf16 out ----
        unsigned short (&As)[64][40]  = *(unsigned short(*)[64][40])(LDS);
        unsigned short (&Bs)[128][40] = *(unsigned short(*)[128][40])(LDS + 2560);

        const int t = bid - 2100;
        int m0, n0, Ncols;
        const float* A2p = nullptr;
        const unsigned short* Bp; const float* bias; unsigned short* C;
        if (t < 300) {
            m0 = (t >> 2)*64; n0 = (t & 3)*128;
            A2p = pos; Bp = wtqk; bias = bqk; C = qk_bf; Ncols = 512;
        } else {
            int tt = t - 300;
            m0 = (tt >> 1)*64; n0 = (tt & 1)*128;
            Bp = wtv; bias = bv; C = v_bf; Ncols = 256;
        }

        const int arow = tid >> 2, aseg = (tid & 3) * 8;
        const int brow = tid >> 1, bseg = (tid & 1) * 16;
        const bool a_ok = true, b_ok = true;
        const int K = 256;
        const float*          aptr  = h_in + (size_t)(m0 + arow)*256 + aseg;
        const float*          aptr2 = A2p ? A2p + (size_t)(m0 + arow)*256 + aseg : (const float*)0;
        const unsigned short* bptr  = Bp + (size_t)(n0 + brow)*256 + bseg;

        f32x4 acc[2][4];
        #pragma unroll
        for (int m = 0; m < 2; ++m)
            #pragma unroll
            for (int n = 0; n < 4; ++n)
                acc[m][n] = (f32x4){0.f, 0.f, 0.f, 0.f};
        float4 avA0, avB0, avA1, avB1;
        ushort8_t bvA0, bvB0, bvA1, bvB1;

        GEMM_KLOOP();

        #pragma unroll
        for (int n = 0; n < 4; ++n) {
            int col = n0 + wc*64 + n*16 + fr;
            float bcol = bias[col];
            #pragma unroll
            for (int m = 0; m < 2; ++m) {
                int rbase = m0 + wr*32 + m*16 + fq*4;
                #pragma unroll
                for (int r = 0; r < 4; ++r)
                    C[(size_t)(rbase + r) * Ncols + col] = f2b(acc[m][n][r] + bcol);
            }
        }
    }
}

// ---------------- fc1: GEMM + bias + relu -> bf16 out (exact shapes) ---------
__global__ __launch_bounds__(256) void gemm_relu_bf16(
    const float* __restrict__ A, const unsigned short* __restrict__ WT,
    const float* __restrict__ bias, unsigned short* __restrict__ OUT,
    int M, int N, int K)
{
    __shared__ unsigned short As[64][40];
    __shared__ unsigned short Bs[128][40];
    const float* A2 = nullptr;
    GEMM_PREAMBLE();
    GEMM_KLOOP();

    #pragma unroll
    for (int n = 0; n < 4; ++n) {
        int col = n0 + wc*64 + n*16 + fr;
        float bcol = bias[col];
        #pragma unroll
        for (int m = 0; m < 2; ++m) {
            int rbase = m0 + wr*32 + m*16 + fq*4;
            #pragma unroll
            for (int r = 0; r < 4; ++r)
                OUT[(size_t)(rbase + r) * N + col] = f2b(fmaxf(acc[m][n][r] + bcol, 0.f));
        }
    }
}

// ================= fused GEMM(N=256) + residual add + LayerNorm ==============
#define GLN16_COMPUTE() do {                                                   \
    bf16x8 af = *(const bf16x8*)&As[fr][fq*8];                                 \
    _Pragma("unroll") for (int n = 0; n < 4; ++n) {                            \
        bf16x8 bfv = *(const bf16x8*)&Bs[w*64 + n*16 + fr][fq*8];              \
        acc[n] = __builtin_amdgcn_mfma_f32_16x16x32_bf16(af, bfv, acc[n], 0, 0, 0); \
    }                                                                          \
} while (0)

#define GLN16_EPILOGUE()                                                       \
    float gcol[4], bcol2[4], biascol[4];                                       \
    _Pragma("unroll") for (int n = 0; n < 4; ++n) {                            \
        int col = w*64 + n*16 + fr;                                            \
        biascol[n] = bias[col]; gcol[n] = g[col]; bcol2[n] = bb[col];          \
    }                                                                          \
    _Pragma("unroll") for (int r = 0; r < 4; ++r) {                            \
        int row = fq*4 + r;                                                    \
        float s = 0.f, sq = 0.f;                                               \
        _Pragma("unroll") for (int n = 0; n < 4; ++n) {                        \
            int col = w*64 + n*16 + fr;                                        \
            float vv = acc[n][r] + biascol[n]                                  \
                     + X[(size_t)(m0 + row)*256 + col];                        \
            acc[n][r] = vv; s += vv; sq += vv*vv;                              \
        }                                                                      \
        s  += __shfl_xor(s, 1);  sq += __shfl_xor(sq, 1);                      \
        s  += __shfl_xor(s, 2);  sq += __shfl_xor(sq, 2);                      \
        s  += __shfl_xor(s, 4);  sq += __shfl_xor(sq, 4);                      \
        s  += __shfl_xor(s, 8);  sq += __shfl_xor(sq, 8);                      \
        if (fr == 0) { psum[row][w] = s; psq[row][w] = sq; }                   \
    }                                                                          \
    __syncthreads();                                                           \
    _Pragma("unroll") for (int r = 0; r < 4; ++r) {                            \
        int row = fq*4 + r;                                                    \
        float mean = (psum[row][0]+psum[row][1]+psum[row][2]+psum[row][3]) * (1.0f/256.0f); \
        float ex2  = (psq[row][0]+psq[row][1]+psq[row][2]+psq[row][3]) * (1.0f/256.0f);     \
        float rstd = rsqrtf(ex2 - mean*mean + 1e-5f);                          \
        _Pragma("unroll") for (int n = 0; n < 4; ++n) {                        \
            int col = w*64 + n*16 + fr;                                        \
            OUT[(size_t)(m0 + row)*256 + col] =                                \
                (acc[n][r] - mean)*rstd*gcol[n] + bcol2[n];                    \
        }                                                                      \
    }

__global__ __launch_bounds__(256) void gemm_ln_f32A(
    const float* __restrict__ A, const unsigned short* __restrict__ WT,
    const float* __restrict__ bias, const float* __restrict__ X,
    const float* __restrict__ g, const float* __restrict__ bb,
    float* __restrict__ OUT, int K)
{
    __shared__ unsigned short As[16][40];
    __shared__ unsigned short Bs[256][40];
    __shared__ float psum[16][4], psq[16][4];

    const int tid  = threadIdx.x;
    const int lane = tid & 63;
    const int w    = tid >> 6;
    const int m0   = blockIdx.x * 16;
    const int fr   = lane & 15, fq = lane >> 4;
    const bool astage = tid < 64;
    const int arow = (tid >> 2) & 15, aseg = (tid & 3) * 8;
    const float*          aptr = A  + (size_t)(m0 + arow)*K + aseg;
    const unsigned short* bptr = WT + (size_t)tid*K;

    f32x4 acc[4];
    #pragma unroll
    for (int n = 0; n < 4; ++n) acc[n] = (f32x4){0.f, 0.f, 0.f, 0.f};

    float4 a0x = {0,0,0,0}, a0y = {0,0,0,0}, a1x = {0,0,0,0}, a1y = {0,0,0,0};
    ushort8_t b0[4], b1[4];

    if (astage) { a0x = *(const float4*)(aptr); a0y = *(const float4*)(aptr + 4); }
    #pragma unroll
    for (int j = 0; j < 4; ++j) b0[j] = *(const ushort8_t*)(bptr + j*8);
    for (int k0 = 0; k0 < K; k0 += 64) {
        __syncthreads();
        if (astage) {
            ushort8_t ac;
            ac[0]=f2b(a0x.x); ac[1]=f2b(a0x.y); ac[2]=f2b(a0x.z); ac[3]=f2b(a0x.w);
            ac[4]=f2b(a0y.x); ac[5]=f2b(a0y.y); ac[6]=f2b(a0y.z); ac[7]=f2b(a0y.w);
            *(ushort8_t*)&As[arow][aseg] = ac;
        }
        #pragma unroll
        for (int j = 0; j < 4; ++j) *(ushort8_t*)&Bs[tid][j*8] = b0[j];
        if (astage) { a1x = *(const float4*)(aptr + k0 + 32); a1y = *(const float4*)(aptr + k0 + 36); }
        #pragma unroll
        for (int j = 0; j < 4; ++j) b1[j] = *(const ushort8_t*)(bptr + k0 + 32 + j*8);
        __syncthreads();
        GLN16_COMPUTE();
        __syncthreads();
        if (astage) {
            ushort8_t ac;
            ac[0]=f2b(a1x.x); ac[1]=f2b(a1x.y); ac[2]=f2b(a1x.z); ac[3]=f2b(a1x.w);
            ac[4]=f2b(a1y.x); ac[5]=f2b(a1y.y); ac[6]=f2b(a1y.z); ac[7]=f2b(a1y.w);
            *(ushort8_t*)&As[arow][aseg] = ac;
        }
        #pragma unroll
        for (int j = 0; j < 4; ++j) *(ushort8_t*)&Bs[tid][j*8] = b1[j];
        if (k0 + 64 < K) {
            if (astage) { a0x = *(const float4*)(aptr + k0 + 64); a0y = *(const float4*)(aptr + k0 + 68); }
            #pragma unroll
            for (int j = 0; j < 4; ++j) b0[j] = *(const ushort8_t*)(bptr + k0 + 64 + j*8);
        }
        __syncthreads();
        GLN16_COMPUTE();
    }

    GLN16_EPILOGUE();
}

__global__ __launch_bounds__(256) void gemm_ln_bf16A(
    const unsigned short* __restrict__ A, const unsigned short* __restrict__ WT,
    const float* __restrict__ bias, const float* __restrict__ X,
    const float* __restrict__ g, const float* __restrict__ bb,
    float* __restrict__ OUT, int K)
{
    __shared__ unsigned short As[16][40];
    __shared__ unsigned short Bs[256][40];
    __shared__ float psum[16][4], psq[16][4];

    const int tid  = threadIdx.x;
    const int lane = tid & 63;
    const int w    = tid >> 6;
    const int m0   = blockIdx.x * 16;
    const int fr   = lane & 15, fq = lane >> 4;
    const bool astage = tid < 64;
    const int arow = (tid >> 2) & 15, aseg = (tid & 3) * 8;
    const unsigned short* aptr = A  + (size_t)(m0 + arow)*K + aseg;
    const unsigned short* bptr = WT + (size_t)tid*K;

    f32x4 acc[4];
    #pragma unroll
    for (int n = 0; n < 4; ++n) acc[n] = (f32x4){0.f, 0.f, 0.f, 0.f};

    ushort8_t a0, a1, b0[4], b1[4];
    #pragma unroll
    for (int j = 0; j < 8; ++j) { a0[j] = 0; a1[j] = 0; }

    if (astage) a0 = *(const ushort8_t*)(aptr);
    #pragma unroll
    for (int j = 0; j < 4; ++j) b0[j] = *(const ushort8_t*)(bptr + j*8);
    for (int k0 = 0; k0 < K; k0 += 64) {
        __syncthreads();
        if (astage) *(ushort8_t*)&As[arow][aseg] = a0;
        #pragma unroll
        for (int j = 0; j < 4; ++j) *(ushort8_t*)&Bs[tid][j*8] = b0[j];
        if (astage) a1 = *(const ushort8_t*)(aptr + k0 + 32);
        #pragma unroll
        for (int j = 0; j < 4; ++j) b1[j] = *(const ushort8_t*)(bptr + k0 + 32 + j*8);
        __syncthreads();
        GLN16_COMPUTE();
        __syncthreads();
        if (astage) *(ushort8_t*)&As[arow][aseg] = a1;
        #pragma unroll
        for (int j = 0; j < 4; ++j) *(ushort8_t*)&Bs[tid][j*8] = b1[j];
        if (k0 + 64 < K) {
            if (astage) a0 = *(const ushort8_t*)(aptr + k0 + 64);
            #pragma unroll
            for (int j = 0; j < 4; ++j) b0[j] = *(const ushort8_t*)(bptr + k0 + 64 + j*8);
        }
        __syncthreads();
        GLN16_COMPUTE();
    }

    GLN16_EPILOGUE();
}

// ---------------- self attention via MFMA (bf16 in, bf16 out) ----------------
__global__ __launch_bounds__(256) void self_attn_kernel(
    const unsigned short* __restrict__ qk, const unsigned short* __restrict__ v,
    unsigned short* __restrict__ sa)
{
    __shared__ unsigned short k_sw[304*32];      // K bf16, 16B-unit XOR swizzled
    __shared__ unsigned short vt[32][312];       // V^T bf16: [d][key]
    __shared__ unsigned short p_all[4][16][312]; // per-wave P: [q_local][key]

    const int bid  = blockIdx.x;
    const int part = bid % 5;
    const int bh   = bid / 5;
    const int h    = bh & 7;
    const int b    = bh >> 3;
    const int tid  = threadIdx.x;
    const int lane = tid & 63;
    const int w    = tid >> 6;
    const int g    = lane >> 4;   // 0..3
    const int fr   = lane & 15;

    const size_t qbase = (size_t)b*NQ_*512 + h*DH_;
    const size_t kbase = qbase + 256;
    const size_t vbase = (size_t)b*NQ_*D_ + h*DH_;
    const size_t sbase = (size_t)b*NQ_*D_ + h*DH_;

    for (int i = tid; i < 1216; i += 256) {
        int r = i >> 2, u = i & 3;
        ushort8_t kb;
        if (r < NQ_) {
            kb = *(const ushort8_t*)(qk + kbase + (size_t)r*512 + u*8);
        } else {
            #pragma unroll
            for (int j = 0; j < 8; ++j) kb[j] = 0;
        }
        int su = u ^ ((r >> 1) & 3);
        *(ushort8_t*)&k_sw[r*32 + su*8] = kb;
    }
    for (int i = tid; i < 1216; i += 256) {
        int kk = i >> 2, u = i & 3;
        if (kk < NQ_) {
            ushort8_t vv = *(const ushort8_t*)(v + vbase + (size_t)kk*D_ + u*8);
            #pragma unroll
            for (int j = 0; j < 8; ++j) vt[u*8 + j][kk] = vv[j];
        } else {
            #pragma unroll
            for (int j = 0; j < 8; ++j) vt[u*8 + j][kk] = 0;
        }
    }
    __syncthreads();

    const int q0 = part*64 + w*16;
    const int qi = q0 + fr;
    bf16x8 qf;
    if (qi < NQ_) {
        const float scale = 0.17677669529663687f;
        ushort8_t q8 = *(const ushort8_t*)(qk + qbase + (size_t)qi*512 + g*8);
        #pragma unroll
        for (int j = 0; j < 8; ++j) qf[j] = (short)f2b(b2f(q8[j]) * scale);
    } else {
        #pragma unroll
        for (int j = 0; j < 8; ++j) qf[j] = 0;
    }

    const int ksw_u = g ^ ((fr >> 1) & 3);
    f32x4 acc[19];
    #pragma unroll
    for (int t = 0; t < 19; ++t) acc[t] = (f32x4){0.f,0.f,0.f,0.f};
    #pragma unroll
    for (int t = 0; t < 19; ++t) {
        int row = t*16 + fr;
        bf16x8 kf = *(const bf16x8*)&k_sw[row*32 + ksw_u*8];
        acc[t] = __builtin_amdgcn_mfma_f32_16x16x32_bf16(kf, qf, acc[t], 0, 0, 0);
    }
    if (g == 3) acc[18] = (f32x4){-1e30f, -1e30f, -1e30f, -1e30f};

    float m = -1e30f;
    #pragma unroll
    for (int t = 0; t < 19; ++t) {
        #pragma unroll
        for (int r = 0; r < 4; ++r) m = fmaxf(m, acc[t][r]);
    }
    m = fmaxf(m, __shfl_xor(m, 16));
    m = fmaxf(m, __shfl_xor(m, 32));
    float lsum = 0.f;
    #pragma unroll
    for (int t = 0; t < 19; ++t) {
        #pragma unroll
        for (int r = 0; r < 4; ++r) {
            float e = __expf(acc[t][r] - m);
            acc[t][r] = e;
            lsum += e;
        }
    }
    lsum += __shfl_xor(lsum, 16);
    lsum += __shfl_xor(lsum, 32);
    float inv = 1.0f / lsum;

    #pragma unroll
    for (int t = 0; t < 19; ++t) {
        ushort4_t pw = { f2b(acc[t][0]*inv), f2b(acc[t][1]*inv),
                         f2b(acc[t][2]*inv), f2b(acc[t][3]*inv) };
        *(ushort4_t*)&p_all[w][fr][t*16 + g*4] = pw;
    }

    f32x4 o0 = (f32x4){0.f,0.f,0.f,0.f};
    f32x4 o1 = (f32x4){0.f,0.f,0.f,0.f};
    #pragma unroll
    for (int ks = 0; ks < 10; ++ks) {
        int kb = ks*32 + g*8;
        bf16x8 pf, vf0, vf1;
        if (kb < 304) {
            pf  = *(const bf16x8*)&p_all[w][fr][kb];
            vf0 = *(const bf16x8*)&vt[fr][kb];
            vf1 = *(const bf16x8*)&vt[16 + fr][kb];
        } else {
            #pragma unroll
            for (int j = 0; j < 8; ++j) { pf[j] = 0; vf0[j] = 0; vf1[j] = 0; }
        }
        o0 = __builtin_amdgcn_mfma_f32_16x16x32_bf16(pf, vf0, o0, 0, 0, 0);
        o1 = __builtin_amdgcn_mfma_f32_16x16x32_bf16(pf, vf1, o1, 0, 0, 0);
    }

    #pragma unroll
    for (int r = 0; r < 4; ++r) {
        int qo = q0 + g*4 + r;
        if (qo < NQ_) {
            sa[sbase + (size_t)qo*D_ + fr]      = f2b(o0[r]);
            sa[sbase + (size_t)qo*D_ + 16 + fr] = f2b(o1[r]);
        }
    }
}

// ---------------- deformable bilinear sampling: 4 d's per thread -------------
// 8 lanes per (b,q,h); lane covers d = {4*l8 .. 4*l8+3} via 8B gathers.
__global__ __launch_bounds__(256) void deform_kernel(
    const unsigned short* __restrict__ value, const float* __restrict__ oa,
    const float* __restrict__ refp, float* __restrict__ dout)
{
    int gid = blockIdx.x*256 + threadIdx.x;
    int l8 = gid & 7;
    int grp = gid >> 3;            // (b*NQ+q)*8 + h
    int h = grp & 7;
    int bq = grp >> 3;
    int qq = bq % NQ_;
    int b  = bq / NQ_;
    int d0 = l8*4;

    const int starts[3] = {0, 6400, 8000};
    const int Hs[3] = {80, 40, 20};

    const float* offp = oa + (size_t)(b*NQ_+qq)*288 + h*24;
    const float* awp  = oa + (size_t)(b*NQ_+qq)*288 + 192 + h*12;
    const float* refq = refp + (size_t)(b*NQ_+qq)*(L_*2);
    const unsigned short* vb = value + ((size_t)(b*NH_ + h)*S_)*DH_ + d0;

    float av[12];
    float mx = -1e30f;
    #pragma unroll
    for (int i = 0; i < 12; ++i) { av[i] = awp[i]; mx = fmaxf(mx, av[i]); }
    float ssum = 0.f;
    #pragma unroll
    for (int i = 0; i < 12; ++i) { av[i] = __expf(av[i]-mx); ssum += av[i]; }
    float sinv = 1.f / ssum;

    float acc0 = 0.f, acc1 = 0.f, acc2 = 0.f, acc3 = 0.f;
    #pragma unroll
    for (int l = 0; l < L_; l++) {
        int Hl = Hs[l], Wl = Hs[l];
        float rx = refq[l*2+0], ry = refq[l*2+1];
        const unsigned short* vlb = vb + (size_t)starts[l]*DH_;
        #pragma unroll
        for (int p = 0; p < P_; p++) {
            float ox = offp[(l*P_+p)*2+0], oy = offp[(l*P_+p)*2+1];
            float a  = av[l*P_+p] * sinv;
            float x = (rx + ox/(float)Wl)*(float)Wl - 0.5f;
            float y = (ry + oy/(float)Hl)*(float)Hl - 0.5f;
            float x0 = floorf(x), y0 = floorf(y);
            #pragma unroll
            for (int dy = 0; dy < 2; dy++) {
                #pragma unroll
                for (int dx = 0; dx < 2; dx++) {
                    float xi = x0 + dx, yi = y0 + dy;
                    float wgt = (1.f - fabsf(x-xi))*(1.f - fabsf(y-yi));
                    bool valid = (xi >= 0.f) && (xi < (float)Wl) && (yi >= 0.f) && (yi < (float)Hl);
                    if (valid && wgt != 0.f) {
                        int ix = (int)xi, iy = (int)yi;
                        uint2 u2 = *(const uint2*)(vlb + (size_t)(iy*Wl + ix)*DH_);
                        float aw2 = a * wgt;
                        acc0 += aw2 * b2f((unsigned short)(u2.x & 0xffff));
                        acc1 += aw2 * b2f((unsigned short)(u2.x >> 16));
                        acc2 += aw2 * b2f((unsigned short)(u2.y & 0xffff));
                        acc3 += aw2 * b2f((unsigned short)(u2.y >> 16));
                    }
                }
            }
        }
    }
    float4 o = { acc0, acc1, acc2, acc3 };
    *(float4*)&dout[(size_t)grp*32 + d0] = o;
}

// ---------------- launch ----------------
extern "C" void kernel_launch(void* const* d_in, const int* in_sizes, int n_in,
                              void* d_out, int out_size, void* d_ws, size_t ws_size,
                              hipStream_t stream) {
    (void)in_sizes; (void)n_in; (void)out_size; (void)ws_size;
    const float* h_in  = (const float*)d_in[0];
    const float* pos   = (const float*)d_in[1];
    const float* ehs   = (const float*)d_in[2];
    const float* refp  = (const float*)d_in[3];
    // d_in[4] = spatial_shapes (hardcoded)
    const float* wq    = (const float*)d_in[5];
    const float* bq    = (const float*)d_in[6];
    const float* wk    = (const float*)d_in[7];
    const float* bk    = (const float*)d_in[8];
    const float* wv    = (const float*)d_in[9];
    const float* bv    = (const float*)d_in[10];
    const float* wo    = (const float*)d_in[11];
    const float* bo    = (const float*)d_in[12];
    const float* ln1g  = (const float*)d_in[13];
    const float* ln1b  = (const float*)d_in[14];
    const float* w_off = (const float*)d_in[15];
    const float* b_off = (const float*)d_in[16];
    const float* w_aw  = (const float*)d_in[17];
    const float* b_aw  = (const float*)d_in[18];
    const float* w_val = (const float*)d_in[19];
    const float* b_val = (const float*)d_in[20];
    const float* w_out = (const float*)d_in[21];
    const float* b_out = (const float*)d_in[22];
    const float* ln2g  = (const float*)d_in[23];
    const float* ln2b  = (const float*)d_in[24];
    const float* w_fc1 = (const float*)d_in[25];
    const float* b_fc1 = (const float*)d_in[26];
    const float* w_fc2 = (const float*)d_in[27];
    const float* b_fc2 = (const float*)d_in[28];
    const float* ln3g  = (const float*)d_in[29];
    const float* ln3b  = (const float*)d_in[30];
    float* out = (float*)d_out;

    float* ws = (float*)d_ws;
    unsigned short* qk_bf = (unsigned short*)(ws + 1*(size_t)NB_);  // 4800x512 bf16
    unsigned short* v_bf  = qk_bf + (size_t)ROWS_*512;              // 4800x256 bf16
    unsigned short* sa_bf = v_bf + (size_t)ROWS_*256;               // 4800x256 bf16
    float* buf_dout = ws + 3*(size_t)NB_;          // deform out (fp32)
    float* buf_h1   = ws + 6*(size_t)NB_;
    float* buf_h2   = ws + 7*(size_t)NB_;
    float* buf_oa   = ws + 8*(size_t)NB_;          // fused off|aw (raw), 4800x288
    unsigned short* fc1_bf = (unsigned short*)(ws + 9*(size_t)NB_ + NB_/2);   // 4800x1024 bf16
    unsigned short* val_bf = (unsigned short*)(ws + 13*(size_t)NB_ + NB_/2);  // (14 NB)

    unsigned short* wtb = (unsigned short*)(ws + 27*(size_t)NB_ + NB_/2);
    unsigned short* wtqk  = wtb;                   // 512x256
    unsigned short* wtv   = wtqk  + 131072;        // 256x256
    unsigned short* wto   = wtv   + 65536;
    unsigned short* wtval = wto   + 65536;
    unsigned short* wtout = wtval + 65536;
    unsigned short* wtoa  = wtout + 65536;         // 288x256
    unsigned short* wtfc1 = wtoa  + 73728;         // 1024x256
    unsigned short* wtfc2 = wtfc1 + 262144;        // 256x1024
    float* bqk = (float*)(wtfc2 + 262144);         // 512
    float* boa = bqk + 512;                        // 288

    dim3 blk(256);

    // ---- fused weight prep (1 launch) ----
    prep_kernel<<<dim3(972), blk, 0, stream>>>(
        wq, wk, wv, wo, w_val, w_out, w_off, w_aw, w_fc1, w_fc2,
        bq, bk, b_off, b_aw,
        wtqk, wtv, wto, wtval, wtout, wtoa, wtfc1, wtfc2, bqk, boa);

    // ---- stage1: value + QK + V (1 launch, 2550 blocks; qkv -> bf16) ----
    stage1_kernel<<<dim3(2550), blk, 0, stream>>>(
        ehs, h_in, pos, wtval, b_val, val_bf, wtqk, bqk, qk_bf, wtv, bv, v_bf);

    // self attention (MFMA, bf16 in/out)
    self_attn_kernel<<<dim3(B_*NH_*5), blk, 0, stream>>>(qk_bf, v_bf, sa_bf);
    // wo projection + residual + LN1 -> h1  (fused, bf16-A, 300 blocks)
    gemm_ln_bf16A<<<dim3(ROWS_/16), blk, 0, stream>>>(
        sa_bf, wto, bo, h_in, ln1g, ln1b, buf_h1, 256);
    // fused offsets + attention weights (A2 = pos); aw stays RAW (softmax in deform)
    gemm_mfma64<<<dim3(3, 75), blk, 0, stream>>>(buf_h1, pos, wtoa, boa, buf_oa, ROWS_, 288, D_, 0);
    // deformable sampling (inline softmax, 4 d's/thread)
    deform_kernel<<<dim3(ROWS_*NH_*8/256), blk, 0, stream>>>(val_bf, buf_oa, refp, buf_dout);
    // ca projection + residual + LN2 -> h2  (fused, 300 blocks)
    gemm_ln_f32A<<<dim3(ROWS_/16), blk, 0, stream>>>(
        buf_dout, wtout, b_out, buf_h1, ln2g, ln2b, buf_h2, 256);
    // FFN: fc1 -> bf16, then fc2 + residual + LN3 -> out (fused, 300 blocks)
    gemm_relu_bf16<<<dim3(8, 75), blk, 0, stream>>>(buf_h2, wtfc1, b_fc1, fc1_bf, ROWS_, FFN_, D_);
    gemm_ln_bf16A<<<dim3(ROWS_/16), blk, 0, stream>>>(
        fc1_bf, wtfc2, b_fc2, buf_h2, ln3g, ln3b, out, FFN_);
}

// Round 18
// 192.795 us; speedup vs baseline: 1.1362x; 1.0001x over previous
//
#include <hip/hip_runtime.h>
#include <hip/hip_bf16.h>
#include <math.h>

// ---------------- problem constants ----------------
#define B_   16
#define NQ_  300
#define D_   256
#define NH_  8
#define DH_  32
#define L_   3
#define P_   4
#define FFN_ 1024
#define S_   8400   // 80*80 + 40*40 + 20*20
#define ROWS_ (B_*NQ_)        // 4800
#define NB_   (ROWS_*D_)      // 1228800 floats per (B,NQ,D) buffer

typedef __attribute__((ext_vector_type(4))) unsigned short ushort4_t;
typedef __attribute__((ext_vector_type(8))) unsigned short ushort8_t;
typedef __attribute__((ext_vector_type(8))) short bf16x8;
typedef __attribute__((ext_vector_type(4))) float f32x4;

__device__ inline unsigned short f2b(float f) {
    __hip_bfloat16 h = __float2bfloat16(f);
    return __builtin_bit_cast(unsigned short, h);
}
__device__ inline float b2f(unsigned short u) {
    union { unsigned u; float f; } c; c.u = ((unsigned)u) << 16; return c.f;
}

// ---------------- fused weight prep: 10 transposes + 2 bias concats ----------
__global__ __launch_bounds__(256) void prep_kernel(
    const float* __restrict__ wq, const float* __restrict__ wk,
    const float* __restrict__ wv, const float* __restrict__ wo,
    const float* __restrict__ w_val, const float* __restrict__ w_out,
    const float* __restrict__ w_off, const float* __restrict__ w_aw,
    const float* __restrict__ w_fc1, const float* __restrict__ w_fc2,
    const float* __restrict__ bq, const float* __restrict__ bk,
    const float* __restrict__ b_off, const float* __restrict__ b_aw,
    unsigned short* __restrict__ wtqk, unsigned short* __restrict__ wtv,
    unsigned short* __restrict__ wto, unsigned short* __restrict__ wtval,
    unsigned short* __restrict__ wtout, unsigned short* __restrict__ wtoa,
    unsigned short* __restrict__ wtfc1, unsigned short* __restrict__ wtfc2,
    float* __restrict__ bqk, float* __restrict__ boa)
{
    const int bid = blockIdx.x;
    if (bid >= 968) {
        int idx = (bid - 968)*256 + threadIdx.x;   // 0..1023
        if (idx < 512) bqk[idx] = (idx < 256) ? bq[idx] : bk[idx-256];
        else { int j = idx - 512; if (j < 288) boa[j] = (j < 192) ? b_off[j] : b_aw[j-192]; }
        return;
    }
    const float* src; unsigned short* dst; int K, N, t;
    if      (bid < 64)  { src=wq;    dst=wtqk;         K=256;  N=256;  t=bid; }
    else if (bid < 128) { src=wk;    dst=wtqk+65536;   K=256;  N=256;  t=bid-64; }
    else if (bid < 192) { src=wv;    dst=wtv;          K=256;  N=256;  t=bid-128; }
    else if (bid < 256) { src=wo;    dst=wto;          K=256;  N=256;  t=bid-192; }
    else if (bid < 320) { src=w_val; dst=wtval;        K=256;  N=256;  t=bid-256; }
    else if (bid < 384) { src=w_out; dst=wtout;        K=256;  N=256;  t=bid-320; }
    else if (bid < 432) { src=w_off; dst=wtoa;         K=256;  N=192;  t=bid-384; }
    else if (bid < 456) { src=w_aw;  dst=wtoa+49152;   K=256;  N=96;   t=bid-432; }
    else if (bid < 712) { src=w_fc1; dst=wtfc1;        K=256;  N=1024; t=bid-456; }
    else                { src=w_fc2; dst=wtfc2;        K=1024; N=256;  t=bid-712; }

    __shared__ unsigned short tl[32][33];
    int tid = threadIdx.x;
    int tx = tid & 31, ty = tid >> 5;           // ty 0..7
    int ntx = N >> 5;
    int n0 = (t % ntx) * 32, k0 = (t / ntx) * 32;
    #pragma unroll
    for (int i = 0; i < 4; ++i)
        tl[tx][ty + i*8] = f2b(src[(size_t)(k0 + ty + i*8)*N + n0 + tx]);
    __syncthreads();
    #pragma unroll
    for (int i = 0; i < 4; ++i)
        dst[(size_t)(n0 + ty + i*8)*K + k0 + tx] = tl[ty + i*8][tx];
}

// ================= 64x128 GEMM macros (4 waves 2x2 of 32x64) ==================
#define GEMM_PREAMBLE()                                                        \
    const int tid  = threadIdx.x;                                              \
    const int lane = tid & 63;                                                 \
    const int w    = tid >> 6;                                                 \
    const int wr   = w >> 1, wc = w & 1;                                       \
    const int m0   = blockIdx.y * 64;                                          \
    const int n0   = blockIdx.x * 128;                                         \
    const int fr   = lane & 15, fq = lane >> 4;                                \
    const int arow = tid >> 2, aseg = (tid & 3) * 8;                           \
    const int brow = tid >> 1, bseg = (tid & 1) * 16;                          \
    const bool a_ok = (m0 + arow) < M;                                         \
    const bool b_ok = (n0 + brow) < N;                                         \
    const float*          aptr  = A  + (size_t)(m0 + arow)*K + aseg;           \
    const float*          aptr2 = A2 ? A2 + (size_t)(m0 + arow)*K + aseg : (const float*)0; \
    const unsigned short* bptr  = WT + (size_t)(n0 + brow)*K + bseg;           \
    f32x4 acc[2][4];                                                           \
    _Pragma("unroll") for (int m = 0; m < 2; ++m)                              \
        _Pragma("unroll") for (int n = 0; n < 4; ++n)                          \
            acc[m][n] = (f32x4){0.f, 0.f, 0.f, 0.f};                           \
    float4 avA0, avB0, avA1, avB1;                                             \
    ushort8_t bvA0, bvB0, bvA1, bvB1;

#define GEMM_LOAD(avA, avB, bvA, bvB, kk) do {                                 \
    if (a_ok) {                                                                \
        avA = *(const float4*)(aptr + (kk));                                   \
        avB = *(const float4*)(aptr + (kk) + 4);                               \
        if (aptr2) {                                                           \
            float4 x2 = *(const float4*)(aptr2 + (kk));                        \
            float4 y2 = *(const float4*)(aptr2 + (kk) + 4);                    \
            avA.x += x2.x; avA.y += x2.y; avA.z += x2.z; avA.w += x2.w;        \
            avB.x += y2.x; avB.y += y2.y; avB.z += y2.z; avB.w += y2.w;        \
        }                                                                      \
    } else { avA = (float4){0,0,0,0}; avB = (float4){0,0,0,0}; }               \
    if (b_ok) { bvA = *(const ushort8_t*)(bptr + (kk));                        \
                bvB = *(const ushort8_t*)(bptr + (kk) + 8); }                  \
    else { _Pragma("unroll") for (int j = 0; j < 8; ++j){bvA[j]=0;bvB[j]=0;} } \
} while (0)

#define GEMM_STORE_LDS(avA, avB, bvA, bvB) do {                                \
    ushort8_t ac;                                                              \
    ac[0]=f2b(avA.x); ac[1]=f2b(avA.y); ac[2]=f2b(avA.z); ac[3]=f2b(avA.w);    \
    ac[4]=f2b(avB.x); ac[5]=f2b(avB.y); ac[6]=f2b(avB.z); ac[7]=f2b(avB.w);    \
    *(ushort8_t*)&As[arow][aseg]     = ac;                                     \
    *(ushort8_t*)&Bs[brow][bseg]     = bvA;                                    \
    *(ushort8_t*)&Bs[brow][bseg + 8] = bvB;                                    \
} while (0)

#define GEMM_COMPUTE() do {                                                    \
    bf16x8 af[2], bfv[4];                                                      \
    _Pragma("unroll") for (int m = 0; m < 2; ++m)                              \
        af[m] = *(const bf16x8*)&As[wr*32 + m*16 + fr][fq*8];                  \
    _Pragma("unroll") for (int n = 0; n < 4; ++n)                              \
        bfv[n] = *(const bf16x8*)&Bs[wc*64 + n*16 + fr][fq*8];                 \
    _Pragma("unroll") for (int m = 0; m < 2; ++m)                              \
        _Pragma("unroll") for (int n = 0; n < 4; ++n)                          \
            acc[m][n] = __builtin_amdgcn_mfma_f32_16x16x32_bf16(               \
                af[m], bfv[n], acc[m][n], 0, 0, 0);                            \
} while (0)

#define GEMM_KLOOP()                                                           \
    GEMM_LOAD(avA0, avB0, bvA0, bvB0, 0);                                      \
    for (int k0 = 0; k0 < K; k0 += 64) {                                       \
        __syncthreads();                                                       \
        GEMM_STORE_LDS(avA0, avB0, bvA0, bvB0);                                \
        GEMM_LOAD(avA1, avB1, bvA1, bvB1, k0 + 32);                            \
        __syncthreads();                                                       \
        GEMM_COMPUTE();                                                        \
        __syncthreads();                                                       \
        GEMM_STORE_LDS(avA1, avB1, bvA1, bvB1);                                \
        if (k0 + 64 < K) GEMM_LOAD(avA0, avB0, bvA0, bvB0, k0 + 64);           \
        __syncthreads();                                                       \
        GEMM_COMPUTE();                                                        \
    }

// ---------------- generic GEMM: C = (A [+A2]) @ WT^T + bias, opt relu --------
__global__ __launch_bounds__(256) void gemm_mfma64(
    const float* __restrict__ A, const float* __restrict__ A2,
    const unsigned short* __restrict__ WT,
    const float* __restrict__ bias, float* __restrict__ C,
    int M, int N, int K, int relu)
{
    __shared__ unsigned short As[64][40];
    __shared__ unsigned short Bs[128][40];
    GEMM_PREAMBLE();
    GEMM_KLOOP();

    #pragma unroll
    for (int n = 0; n < 4; ++n) {
        int col = n0 + wc*64 + n*16 + fr;
        if (col < N) {
            float bcol = bias[col];
            #pragma unroll
            for (int m = 0; m < 2; ++m) {
                int rbase = m0 + wr*32 + m*16 + fq*4;
                #pragma unroll
                for (int r = 0; r < 4; ++r) {
                    int row = rbase + r;
                    if (row < M) {
                        float vv = acc[m][n][r] + bcol;
                        if (relu) vv = fmaxf(vv, 0.f);
                        C[(size_t)row * N + col] = vv;
                    }
                }
            }
        }
    }
}

// ---------------- stage1: val (whole-N 64x256, 51KB LDS) + QK + V ------------
// blocks 0..2099: value GEMM -> bf16 head-major; 2100..2399: QK (bf16 out);
// 2400..2549: V (bf16 out).
__global__ __launch_bounds__(256) void stage1_kernel(
    const float* __restrict__ ehs, const float* __restrict__ h_in,
    const float* __restrict__ pos,
    const unsigned short* __restrict__ wtval, const float* __restrict__ b_val,
    unsigned short* __restrict__ val_bf,
    const unsigned short* __restrict__ wtqk, const float* __restrict__ bqk,
    unsigned short* __restrict__ qk_bf,
    const unsigned short* __restrict__ wtv, const float* __restrict__ bv,
    unsigned short* __restrict__ v_bf)
{
    __shared__ unsigned short LDS[25600];   // 51.2 KB -> 3 blocks/CU

    const int bid  = blockIdx.x;
    const int tid  = threadIdx.x;
    const int lane = tid & 63;
    const int w    = tid >> 6;
    const int wr   = w >> 1, wc = w & 1;
    const int fr   = lane & 15, fq = lane >> 4;

    if (bid < 2100) {
        // ------- value path: 64 rows x 256 cols, K chunks of 64 -------
        unsigned short (&As2)[2][64][40]  = *(unsigned short(*)[2][64][40])(LDS);
        unsigned short (&Bs2)[2][256][40] = *(unsigned short(*)[2][256][40])(LDS + 5120);
        const int m0 = bid * 64;

        f32x4 acc[2][8];
        #pragma unroll
        for (int m = 0; m < 2; ++m)
            #pragma unroll
            for (int n = 0; n < 8; ++n)
                acc[m][n] = (f32x4){0.f, 0.f, 0.f, 0.f};

        for (int kc = 0; kc < 4; ++kc) {
            const int kbase = kc * 64;
            __syncthreads();
            // stage A chunk: 64x64 fp32 -> bf16 (2 units/thread)
            #pragma unroll
            for (int i = 0; i < 2; ++i) {
                int uf = i*256 + tid;              // 0..511
                int row = uf >> 3, j = uf & 7;
                const float* src = ehs + (size_t)(m0 + row)*256 + kbase + j*8;
                float4 x = *(const float4*)src;
                float4 y = *(const float4*)(src + 4);
                ushort8_t u;
                u[0]=f2b(x.x); u[1]=f2b(x.y); u[2]=f2b(x.z); u[3]=f2b(x.w);
                u[4]=f2b(y.x); u[5]=f2b(y.y); u[6]=f2b(y.z); u[7]=f2b(y.w);
                *(ushort8_t*)&As2[j>>2][row][(j&3)*8] = u;
            }
            // stage B chunk: 256x64 bf16 (8 units/thread)
            #pragma unroll
            for (int i = 0; i < 8; ++i) {
                int uf = i*256 + tid;              // 0..2047
                int row = uf >> 3, j = uf & 7;
                ushort8_t u = *(const ushort8_t*)(wtval + (size_t)row*256 + kbase + j*8);
                *(ushort8_t*)&Bs2[j>>2][row][(j&3)*8] = u;
            }
            __syncthreads();
            // compute: 2 k-steps x 16 MFMA
            #pragma unroll
            for (int ks = 0; ks < 2; ++ks) {
                bf16x8 af[2], bfv[8];
                #pragma unroll
                for (int m = 0; m < 2; ++m)
                    af[m] = *(const bf16x8*)&As2[ks][wr*32 + m*16 + fr][fq*8];
                #pragma unroll
                for (int n = 0; n < 8; ++n)
                    bfv[n] = *(const bf16x8*)&Bs2[ks][wc*128 + n*16 + fr][fq*8];
                #pragma unroll
                for (int m = 0; m < 2; ++m)
                    #pragma unroll
                    for (int n = 0; n < 8; ++n)
                        acc[m][n] = __builtin_amdgcn_mfma_f32_16x16x32_bf16(
                            af[m], bfv[n], acc[m][n], 0, 0, 0);
            }
        }

        // epilogue: bias + bf16 head-major store
        #pragma unroll
        for (int n = 0; n < 8; ++n) {
            int col = wc*128 + n*16 + fr;          // 0..255
            int hh = col >> 5, dd = col & 31;
            float bcol = b_val[col];
            #pragma unroll
            for (int m = 0; m < 2; ++m) {
                int rbase = m0 + wr*32 + m*16 + fq*4;
                #pragma unroll
                for (int r = 0; r < 4; ++r) {
                    unsigned row = rbase + r;      // 0..134399
                    unsigned bb = row / (unsigned)S_;
                    unsigned ss = row - bb * (unsigned)S_;
                    val_bf[((size_t)(bb*NH_ + hh)*S_ + ss)*DH_ + dd] = f2b(acc[m][n][r] + bcol);
                }
            }
        }
    } else {
        // ------- qkv path: 64x128 tile, proven 2-barrier K-loop, bf16 out ----
        unsigned short (&As)[64][40]  = *(unsigned short(*)[64][40])(LDS);
        unsigned short (&Bs)[128][40] = *(unsigned short(*)[128][40])(LDS + 2560);

        const int t = bid - 2100;
        int m0, n0, Ncols;
        const float* A2p = nullptr;
        const unsigned short* Bp; const float* bias; unsigned short* C;
        if (t < 300) {
            m0 = (t >> 2)*64; n0 = (t & 3)*128;
            A2p = pos; Bp = wtqk; bias = bqk; C = qk_bf; Ncols = 512;
        } else {
            int tt = t - 300;
            m0 = (tt >> 1)*64; n0 = (tt & 1)*128;
            Bp = wtv; bias = bv; C = v_bf; Ncols = 256;
        }

        const int arow = tid >> 2, aseg = (tid & 3) * 8;
        const int brow = tid >> 1, bseg = (tid & 1) * 16;
        const bool a_ok = true, b_ok = true;
        const int K = 256;
        const float*          aptr  = h_in + (size_t)(m0 + arow)*256 + aseg;
        const float*          aptr2 = A2p ? A2p + (size_t)(m0 + arow)*256 + aseg : (const float*)0;
        const unsigned short* bptr  = Bp + (size_t)(n0 + brow)*256 + bseg;

        f32x4 acc[2][4];
        #pragma unroll
        for (int m = 0; m < 2; ++m)
            #pragma unroll
            for (int n = 0; n < 4; ++n)
                acc[m][n] = (f32x4){0.f, 0.f, 0.f, 0.f};
        float4 avA0, avB0, avA1, avB1;
        ushort8_t bvA0, bvB0, bvA1, bvB1;

        GEMM_KLOOP();

        #pragma unroll
        for (int n = 0; n < 4; ++n) {
            int col = n0 + wc*64 + n*16 + fr;
            float bcol = bias[col];
            #pragma unroll
            for (int m = 0; m < 2; ++m) {
                int rbase = m0 + wr*32 + m*16 + fq*4;
                #pragma unroll
                for (int r = 0; r < 4; ++r)
                    C[(size_t)(rbase + r) * Ncols + col] = f2b(acc[m][n][r] + bcol);
            }
        }
    }
}

// ---------------- fc1: GEMM + bias + relu -> bf16 out (exact shapes) ---------
__global__ __launch_bounds__(256) void gemm_relu_bf16(
    const float* __restrict__ A, const unsigned short* __restrict__ WT,
    const float* __restrict__ bias, unsigned short* __restrict__ OUT,
    int M, int N, int K)
{
    __shared__ unsigned short As[64][40];
    __shared__ unsigned short Bs[128][40];
    const float* A2 = nullptr;
    GEMM_PREAMBLE();
    GEMM_KLOOP();

    #pragma unroll
    for (int n = 0; n < 4; ++n) {
        int col = n0 + wc*64 + n*16 + fr;
        float bcol = bias[col];
        #pragma unroll
        for (int m = 0; m < 2; ++m) {
            int rbase = m0 + wr*32 + m*16 + fq*4;
            #pragma unroll
            for (int r = 0; r < 4; ++r)
                OUT[(size_t)(rbase + r) * N + col] = f2b(fmaxf(acc[m][n][r] + bcol, 0.f));
        }
    }
}

// ================= fused GEMM(N=256) + residual add + LayerNorm ==============
#define GLN16_COMPUTE() do {                                                   \
    bf16x8 af = *(const bf16x8*)&As[fr][fq*8];                                 \
    _Pragma("unroll") for (int n = 0; n < 4; ++n) {                            \
        bf16x8 bfv = *(const bf16x8*)&Bs[w*64 + n*16 + fr][fq*8];              \
        acc[n] = __builtin_amdgcn_mfma_f32_16x16x32_bf16(af, bfv, acc[n], 0, 0, 0); \
    }                                                                          \
} while (0)

#define GLN16_EPILOGUE()                                                       \
    float gcol[4], bcol2[4], biascol[4];                                       \
    _Pragma("unroll") for (int n = 0; n < 4; ++n) {                            \
        int col = w*64 + n*16 + fr;                                            \
        biascol[n] = bias[col]; gcol[n] = g[col]; bcol2[n] = bb[col];          \
    }                                                                          \
    _Pragma("unroll") for (int r = 0; r < 4; ++r) {                            \
        int row = fq*4 + r;                                                    \
        float s = 0.f, sq = 0.f;                                               \
        _Pragma("unroll") for (int n = 0; n < 4; ++n) {                        \
            int col = w*64 + n*16 + fr;                                        \
            float vv = acc[n][r] + biascol[n]                                  \
                     + X[(size_t)(m0 + row)*256 + col];                        \
            acc[n][r] = vv; s += vv; sq += vv*vv;                              \
        }                                                                      \
        s  += __shfl_xor(s, 1);  sq += __shfl_xor(sq, 1);                      \
        s  += __shfl_xor(s, 2);  sq += __shfl_xor(sq, 2);                      \
        s  += __shfl_xor(s, 4);  sq += __shfl_xor(sq, 4);                      \
        s  += __shfl_xor(s, 8);  sq += __shfl_xor(sq, 8);                      \
        if (fr == 0) { psum[row][w] = s; psq[row][w] = sq; }                   \
    }                                                                          \
    __syncthreads();                                                           \
    _Pragma("unroll") for (int r = 0; r < 4; ++r) {                            \
        int row = fq*4 + r;                                                    \
        float mean = (psum[row][0]+psum[row][1]+psum[row][2]+psum[row][3]) * (1.0f/256.0f); \
        float ex2  = (psq[row][0]+psq[row][1]+psq[row][2]+psq[row][3]) * (1.0f/256.0f);     \
        float rstd = rsqrtf(ex2 - mean*mean + 1e-5f);                          \
        _Pragma("unroll") for (int n = 0; n < 4; ++n) {                        \
            int col = w*64 + n*16 + fr;                                        \
            OUT[(size_t)(m0 + row)*256 + col] =                                \
                (acc[n][r] - mean)*rstd*gcol[n] + bcol2[n];                    \
        }                                                                      \
    }

__global__ __launch_bounds__(256) void gemm_ln_f32A(
    const float* __restrict__ A, const unsigned short* __restrict__ WT,
    const float* __restrict__ bias, const float* __restrict__ X,
    const float* __restrict__ g, const float* __restrict__ bb,
    float* __restrict__ OUT, int K)
{
    __shared__ unsigned short As[16][40];
    __shared__ unsigned short Bs[256][40];
    __shared__ float psum[16][4], psq[16][4];

    const int tid  = threadIdx.x;
    const int lane = tid & 63;
    const int w    = tid >> 6;
    const int m0   = blockIdx.x * 16;
    const int fr   = lane & 15, fq = lane >> 4;
    const bool astage = tid < 64;
    const int arow = (tid >> 2) & 15, aseg = (tid & 3) * 8;
    const float*          aptr = A  + (size_t)(m0 + arow)*K + aseg;
    const unsigned short* bptr = WT + (size_t)tid*K;

    f32x4 acc[4];
    #pragma unroll
    for (int n = 0; n < 4; ++n) acc[n] = (f32x4){0.f, 0.f, 0.f, 0.f};

    float4 a0x = {0,0,0,0}, a0y = {0,0,0,0}, a1x = {0,0,0,0}, a1y = {0,0,0,0};
    ushort8_t b0[4], b1[4];

    if (astage) { a0x = *(const float4*)(aptr); a0y = *(const float4*)(aptr + 4); }
    #pragma unroll
    for (int j = 0; j < 4; ++j) b0[j] = *(const ushort8_t*)(bptr + j*8);
    for (int k0 = 0; k0 < K; k0 += 64) {
        __syncthreads();
        if (astage) {
            ushort8_t ac;
            ac[0]=f2b(a0x.x); ac[1]=f2b(a0x.y); ac[2]=f2b(a0x.z); ac[3]=f2b(a0x.w);
            ac[4]=f2b(a0y.x); ac[5]=f2b(a0y.y); ac[6]=f2b(a0y.z); ac[7]=f2b(a0y.w);
            *(ushort8_t*)&As[arow][aseg] = ac;
        }
        #pragma unroll
        for (int j = 0; j < 4; ++j) *(ushort8_t*)&Bs[tid][j*8] = b0[j];
        if (astage) { a1x = *(const float4*)(aptr + k0 + 32); a1y = *(const float4*)(aptr + k0 + 36); }
        #pragma unroll
        for (int j = 0; j < 4; ++j) b1[j] = *(const ushort8_t*)(bptr + k0 + 32 + j*8);
        __syncthreads();
        GLN16_COMPUTE();
        __syncthreads();
        if (astage) {
            ushort8_t ac;
            ac[0]=f2b(a1x.x); ac[1]=f2b(a1x.y); ac[2]=f2b(a1x.z); ac[3]=f2b(a1x.w);
            ac[4]=f2b(a1y.x); ac[5]=f2b(a1y.y); ac[6]=f2b(a1y.z); ac[7]=f2b(a1y.w);
            *(ushort8_t*)&As[arow][aseg] = ac;
        }
        #pragma unroll
        for (int j = 0; j < 4; ++j) *(ushort8_t*)&Bs[tid][j*8] = b1[j];
        if (k0 + 64 < K) {
            if (astage) { a0x = *(const float4*)(aptr + k0 + 64); a0y = *(const float4*)(aptr + k0 + 68); }
            #pragma unroll
            for (int j = 0; j < 4; ++j) b0[j] = *(const ushort8_t*)(bptr + k0 + 64 + j*8);
        }
        __syncthreads();
        GLN16_COMPUTE();
    }

    GLN16_EPILOGUE();
}

__global__ __launch_bounds__(256) void gemm_ln_bf16A(
    const unsigned short* __restrict__ A, const unsigned short* __restrict__ WT,
    const float* __restrict__ bias, const float* __restrict__ X,
    const float* __restrict__ g, const float* __restrict__ bb,
    float* __restrict__ OUT, int K)
{
    __shared__ unsigned short As[16][40];
    __shared__ unsigned short Bs[256][40];
    __shared__ float psum[16][4], psq[16][4];

    const int tid  = threadIdx.x;
    const int lane = tid & 63;
    const int w    = tid >> 6;
    const int m0   = blockIdx.x * 16;
    const int fr   = lane & 15, fq = lane >> 4;
    const bool astage = tid < 64;
    const int arow = (tid >> 2) & 15, aseg = (tid & 3) * 8;
    const unsigned short* aptr = A  + (size_t)(m0 + arow)*K + aseg;
    const unsigned short* bptr = WT + (size_t)tid*K;

    f32x4 acc[4];
    #pragma unroll
    for (int n = 0; n < 4; ++n) acc[n] = (f32x4){0.f, 0.f, 0.f, 0.f};

    ushort8_t a0, a1, b0[4], b1[4];
    #pragma unroll
    for (int j = 0; j < 8; ++j) { a0[j] = 0; a1[j] = 0; }

    if (astage) a0 = *(const ushort8_t*)(aptr);
    #pragma unroll
    for (int j = 0; j < 4; ++j) b0[j] = *(const ushort8_t*)(bptr + j*8);
    for (int k0 = 0; k0 < K; k0 += 64) {
        __syncthreads();
        if (astage) *(ushort8_t*)&As[arow][aseg] = a0;
        #pragma unroll
        for (int j = 0; j < 4; ++j) *(ushort8_t*)&Bs[tid][j*8] = b0[j];
        if (astage) a1 = *(const ushort8_t*)(aptr + k0 + 32);
        #pragma unroll
        for (int j = 0; j < 4; ++j) b1[j] = *(const ushort8_t*)(bptr + k0 + 32 + j*8);
        __syncthreads();
        GLN16_COMPUTE();
        __syncthreads();
        if (astage) *(ushort8_t*)&As[arow][aseg] = a1;
        #pragma unroll
        for (int j = 0; j < 4; ++j) *(ushort8_t*)&Bs[tid][j*8] = b1[j];
        if (k0 + 64 < K) {
            if (astage) a0 = *(const ushort8_t*)(aptr + k0 + 64);
            #pragma unroll
            for (int j = 0; j < 4; ++j) b0[j] = *(const ushort8_t*)(bptr + k0 + 64 + j*8);
        }
        __syncthreads();
        GLN16_COMPUTE();
    }

    GLN16_EPILOGUE();
}

// ---------------- self attention via MFMA (bf16 in, bf16 out) ----------------
__global__ __launch_bounds__(256) void self_attn_kernel(
    const unsigned short* __restrict__ qk, const unsigned short* __restrict__ v,
    unsigned short* __restrict__ sa)
{
    __shared__ unsigned short k_sw[304*32];      // K bf16, 16B-unit XOR swizzled
    __shared__ unsigned short vt[32][312];       // V^T bf16: [d][key]
    __shared__ unsigned short p_all[4][16][312]; // per-wave P: [q_local][key]

    const int bid  = blockIdx.x;
    const int part = bid % 5;
    const int bh   = bid / 5;
    const int h    = bh & 7;
    const int b    = bh >> 3;
    const int tid  = threadIdx.x;
    const int lane = tid & 63;
    const int w    = tid >> 6;
    const int g    = lane >> 4;   // 0..3
    const int fr   = lane & 15;

    const size_t qbase = (size_t)b*NQ_*512 + h*DH_;
    const size_t kbase = qbase + 256;
    const size_t vbase = (size_t)b*NQ_*D_ + h*DH_;
    const size_t sbase = (size_t)b*NQ_*D_ + h*DH_;

    for (int i = tid; i < 1216; i += 256) {
        int r = i >> 2, u = i & 3;
        ushort8_t kb;
        if (r < NQ_) {
            kb = *(const ushort8_t*)(qk + kbase + (size_t)r*512 + u*8);
        } else {
            #pragma unroll
            for (int j = 0; j < 8; ++j) kb[j] = 0;
        }
        int su = u ^ ((r >> 1) & 3);
        *(ushort8_t*)&k_sw[r*32 + su*8] = kb;
    }
    for (int i = tid; i < 1216; i += 256) {
        int kk = i >> 2, u = i & 3;
        if (kk < NQ_) {
            ushort8_t vv = *(const ushort8_t*)(v + vbase + (size_t)kk*D_ + u*8);
            #pragma unroll
            for (int j = 0; j < 8; ++j) vt[u*8 + j][kk] = vv[j];
        } else {
            #pragma unroll
            for (int j = 0; j < 8; ++j) vt[u*8 + j][kk] = 0;
        }
    }
    __syncthreads();

    const int q0 = part*64 + w*16;
    const int qi = q0 + fr;
    bf16x8 qf;
    if (qi < NQ_) {
        const float scale = 0.17677669529663687f;
        ushort8_t q8 = *(const ushort8_t*)(qk + qbase + (size_t)qi*512 + g*8);
        #pragma unroll
        for (int j = 0; j < 8; ++j) qf[j] = (short)f2b(b2f(q8[j]) * scale);
    } else {
        #pragma unroll
        for (int j = 0; j < 8; ++j) qf[j] = 0;
    }

    const int ksw_u = g ^ ((fr >> 1) & 3);
    f32x4 acc[19];
    #pragma unroll
    for (int t = 0; t < 19; ++t) acc[t] = (f32x4){0.f,0.f,0.f,0.f};
    #pragma unroll
    for (int t = 0; t < 19; ++t) {
        int row = t*16 + fr;
        bf16x8 kf = *(const bf16x8*)&k_sw[row*32 + ksw_u*8];
        acc[t] = __builtin_amdgcn_mfma_f32_16x16x32_bf16(kf, qf, acc[t], 0, 0, 0);
    }
    if (g == 3) acc[18] = (f32x4){-1e30f, -1e30f, -1e30f, -1e30f};

    float m = -1e30f;
    #pragma unroll
    for (int t = 0; t < 19; ++t) {
        #pragma unroll
        for (int r = 0; r < 4; ++r) m = fmaxf(m, acc[t][r]);
    }
    m = fmaxf(m, __shfl_xor(m, 16));
    m = fmaxf(m, __shfl_xor(m, 32));
    float lsum = 0.f;
    #pragma unroll
    for (int t = 0; t < 19; ++t) {
        #pragma unroll
        for (int r = 0; r < 4; ++r) {
            float e = __expf(acc[t][r] - m);
            acc[t][r] = e;
            lsum += e;
        }
    }
    lsum += __shfl_xor(lsum, 16);
    lsum += __shfl_xor(lsum, 32);
    float inv = 1.0f / lsum;

    #pragma unroll
    for (int t = 0; t < 19; ++t) {
        ushort4_t pw = { f2b(acc[t][0]*inv), f2b(acc[t][1]*inv),
                         f2b(acc[t][2]*inv), f2b(acc[t][3]*inv) };
        *(ushort4_t*)&p_all[w][fr][t*16 + g*4] = pw;
    }

    f32x4 o0 = (f32x4){0.f,0.f,0.f,0.f};
    f32x4 o1 = (f32x4){0.f,0.f,0.f,0.f};
    #pragma unroll
    for (int ks = 0; ks < 10; ++ks) {
        int kb = ks*32 + g*8;
        bf16x8 pf, vf0, vf1;
        if (kb < 304) {
            pf  = *(const bf16x8*)&p_all[w][fr][kb];
            vf0 = *(const bf16x8*)&vt[fr][kb];
            vf1 = *(const bf16x8*)&vt[16 + fr][kb];
        } else {
            #pragma unroll
            for (int j = 0; j < 8; ++j) { pf[j] = 0; vf0[j] = 0; vf1[j] = 0; }
        }
        o0 = __builtin_amdgcn_mfma_f32_16x16x32_bf16(pf, vf0, o0, 0, 0, 0);
        o1 = __builtin_amdgcn_mfma_f32_16x16x32_bf16(pf, vf1, o1, 0, 0, 0);
    }

    #pragma unroll
    for (int r = 0; r < 4; ++r) {
        int qo = q0 + g*4 + r;
        if (qo < NQ_) {
            sa[sbase + (size_t)qo*D_ + fr]      = f2b(o0[r]);
            sa[sbase + (size_t)qo*D_ + 16 + fr] = f2b(o1[r]);
        }
    }
}

// ---------------- deformable bilinear sampling: 4 d's per thread, bf16 out ---
// 8 lanes per (b,q,h); lane covers d = {4*l8 .. 4*l8+3} via 8B gathers.
__global__ __launch_bounds__(256) void deform_kernel(
    const unsigned short* __restrict__ value, const float* __restrict__ oa,
    const float* __restrict__ refp, unsigned short* __restrict__ dout)
{
    int gid = blockIdx.x*256 + threadIdx.x;
    int l8 = gid & 7;
    int grp = gid >> 3;            // (b*NQ+q)*8 + h
    int h = grp & 7;
    int bq = grp >> 3;
    int qq = bq % NQ_;
    int b  = bq / NQ_;
    int d0 = l8*4;

    const int starts[3] = {0, 6400, 8000};
    const int Hs[3] = {80, 40, 20};

    const float* offp = oa + (size_t)(b*NQ_+qq)*288 + h*24;
    const float* awp  = oa + (size_t)(b*NQ_+qq)*288 + 192 + h*12;
    const float* refq = refp + (size_t)(b*NQ_+qq)*(L_*2);
    const unsigned short* vb = value + ((size_t)(b*NH_ + h)*S_)*DH_ + d0;

    float av[12];
    float mx = -1e30f;
    #pragma unroll
    for (int i = 0; i < 12; ++i) { av[i] = awp[i]; mx = fmaxf(mx, av[i]); }
    float ssum = 0.f;
    #pragma unroll
    for (int i = 0; i < 12; ++i) { av[i] = __expf(av[i]-mx); ssum += av[i]; }
    float sinv = 1.f / ssum;

    float acc0 = 0.f, acc1 = 0.f, acc2 = 0.f, acc3 = 0.f;
    #pragma unroll
    for (int l = 0; l < L_; l++) {
        int Hl = Hs[l], Wl = Hs[l];
        float rx = refq[l*2+0], ry = refq[l*2+1];
        const unsigned short* vlb = vb + (size_t)starts[l]*DH_;
        #pragma unroll
        for (int p = 0; p < P_; p++) {
            float ox = offp[(l*P_+p)*2+0], oy = offp[(l*P_+p)*2+1];
            float a  = av[l*P_+p] * sinv;
            float x = (rx + ox/(float)Wl)*(float)Wl - 0.5f;
            float y = (ry + oy/(float)Hl)*(float)Hl - 0.5f;
            float x0 = floorf(x), y0 = floorf(y);
            #pragma unroll
            for (int dy = 0; dy < 2; dy++) {
                #pragma unroll
                for (int dx = 0; dx < 2; dx++) {
                    float xi = x0 + dx, yi = y0 + dy;
                    float wgt = (1.f - fabsf(x-xi))*(1.f - fabsf(y-yi));
                    bool valid = (xi >= 0.f) && (xi < (float)Wl) && (yi >= 0.f) && (yi < (float)Hl);
                    if (valid && wgt != 0.f) {
                        int ix = (int)xi, iy = (int)yi;
                        uint2 u2 = *(const uint2*)(vlb + (size_t)(iy*Wl + ix)*DH_);
                        float aw2 = a * wgt;
                        acc0 += aw2 * b2f((unsigned short)(u2.x & 0xffff));
                        acc1 += aw2 * b2f((unsigned short)(u2.x >> 16));
                        acc2 += aw2 * b2f((unsigned short)(u2.y & 0xffff));
                        acc3 += aw2 * b2f((unsigned short)(u2.y >> 16));
                    }
                }
            }
        }
    }
    ushort4_t o = { f2b(acc0), f2b(acc1), f2b(acc2), f2b(acc3) };
    *(ushort4_t*)&dout[(size_t)grp*32 + d0] = o;
}

// ---------------- launch ----------------
extern "C" void kernel_launch(void* const* d_in, const int* in_sizes, int n_in,
                              void* d_out, int out_size, void* d_ws, size_t ws_size,
                              hipStream_t stream) {
    (void)in_sizes; (void)n_in; (void)out_size; (void)ws_size;
    const float* h_in  = (const float*)d_in[0];
    const float* pos   = (const float*)d_in[1];
    const float* ehs   = (const float*)d_in[2];
    const float* refp  = (const float*)d_in[3];
    // d_in[4] = spatial_shapes (hardcoded)
    const float* wq    = (const float*)d_in[5];
    const float* bq    = (const float*)d_in[6];
    const float* wk    = (const float*)d_in[7];
    const float* bk    = (const float*)d_in[8];
    const float* wv    = (const float*)d_in[9];
    const float* bv    = (const float*)d_in[10];
    const float* wo    = (const float*)d_in[11];
    const float* bo    = (const float*)d_in[12];
    const float* ln1g  = (const float*)d_in[13];
    const float* ln1b  = (const float*)d_in[14];
    const float* w_off = (const float*)d_in[15];
    const float* b_off = (const float*)d_in[16];
    const float* w_aw  = (const float*)d_in[17];
    const float* b_aw  = (const float*)d_in[18];
    const float* w_val = (const float*)d_in[19];
    const float* b_val = (const float*)d_in[20];
    const float* w_out = (const float*)d_in[21];
    const float* b_out = (const float*)d_in[22];
    const float* ln2g  = (const float*)d_in[23];
    const float* ln2b  = (const float*)d_in[24];
    const float* w_fc1 = (const float*)d_in[25];
    const float* b_fc1 = (const float*)d_in[26];
    const float* w_fc2 = (const float*)d_in[27];
    const float* b_fc2 = (const float*)d_in[28];
    const float* ln3g  = (const float*)d_in[29];
    const float* ln3b  = (const float*)d_in[30];
    float* out = (float*)d_out;

    float* ws = (float*)d_ws;
    unsigned short* qk_bf = (unsigned short*)(ws + 1*(size_t)NB_);  // 4800x512 bf16
    unsigned short* v_bf  = qk_bf + (size_t)ROWS_*512;              // 4800x256 bf16
    unsigned short* sa_bf = v_bf + (size_t)ROWS_*256;               // 4800x256 bf16
    unsigned short* dout_bf = sa_bf + (size_t)ROWS_*256;            // 4800x256 bf16
    float* buf_h1   = ws + 6*(size_t)NB_;
    float* buf_h2   = ws + 7*(size_t)NB_;
    float* buf_oa   = ws + 8*(size_t)NB_;          // fused off|aw (raw), 4800x288
    unsigned short* fc1_bf = (unsigned short*)(ws + 9*(size_t)NB_ + NB_/2);   // 4800x1024 bf16
    unsigned short* val_bf = (unsigned short*)(ws + 13*(size_t)NB_ + NB_/2);  // (14 NB)

    unsigned short* wtb = (unsigned short*)(ws + 27*(size_t)NB_ + NB_/2);
    unsigned short* wtqk  = wtb;                   // 512x256
    unsigned short* wtv   = wtqk  + 131072;        // 256x256
    unsigned short* wto   = wtv   + 65536;
    unsigned short* wtval = wto   + 65536;
    unsigned short* wtout = wtval + 65536;
    unsigned short* wtoa  = wtout + 65536;         // 288x256
    unsigned short* wtfc1 = wtoa  + 73728;         // 1024x256
    unsigned short* wtfc2 = wtfc1 + 262144;        // 256x1024
    float* bqk = (float*)(wtfc2 + 262144);         // 512
    float* boa = bqk + 512;                        // 288

    dim3 blk(256);

    // ---- fused weight prep (1 launch) ----
    prep_kernel<<<dim3(972), blk, 0, stream>>>(
        wq, wk, wv, wo, w_val, w_out, w_off, w_aw, w_fc1, w_fc2,
        bq, bk, b_off, b_aw,
        wtqk, wtv, wto, wtval, wtout, wtoa, wtfc1, wtfc2, bqk, boa);

    // ---- stage1: value + QK + V (1 launch, 2550 blocks; qkv -> bf16) ----
    stage1_kernel<<<dim3(2550), blk, 0, stream>>>(
        ehs, h_in, pos, wtval, b_val, val_bf, wtqk, bqk, qk_bf, wtv, bv, v_bf);

    // self attention (MFMA, bf16 in/out)
    self_attn_kernel<<<dim3(B_*NH_*5), blk, 0, stream>>>(qk_bf, v_bf, sa_bf);
    // wo projection + residual + LN1 -> h1  (fused, bf16-A, 300 blocks)
    gemm_ln_bf16A<<<dim3(ROWS_/16), blk, 0, stream>>>(
        sa_bf, wto, bo, h_in, ln1g, ln1b, buf_h1, 256);
    // fused offsets + attention weights (A2 = pos); aw stays RAW (softmax in deform)
    gemm_mfma64<<<dim3(3, 75), blk, 0, stream>>>(buf_h1, pos, wtoa, boa, buf_oa, ROWS_, 288, D_, 0);
    // deformable sampling (inline softmax, 4 d's/thread, bf16 out)
    deform_kernel<<<dim3(ROWS_*NH_*8/256), blk, 0, stream>>>(val_bf, buf_oa, refp, dout_bf);
    // ca projection + residual + LN2 -> h2  (fused, bf16-A, 300 blocks)
    gemm_ln_bf16A<<<dim3(ROWS_/16), blk, 0, stream>>>(
        dout_bf, wtout, b_out, buf_h1, ln2g, ln2b, buf_h2, 256);
    // FFN: fc1 -> bf16, then fc2 + residual + LN3 -> out (fused, 300 blocks)
    gemm_relu_bf16<<<dim3(8, 75), blk, 0, stream>>>(buf_h2, wtfc1, b_fc1, fc1_bf, ROWS_, FFN_, D_);
    gemm_ln_bf16A<<<dim3(ROWS_/16), blk, 0, stream>>>(
        fc1_bf, wtfc2, b_fc2, buf_h2, ln3g, ln3b, out, FFN_);
}